// Round 7
// baseline (538.893 us; speedup 1.0000x reference)
//
#include <hip/hip_runtime.h>
#include <hip/hip_bf16.h>

#define B_ 4
#define S_ 1024
#define D_ 1024
#define H_ 16
#define DH_ 64
#define F_ 4096

typedef unsigned short u16;
typedef unsigned int u32;
typedef __attribute__((ext_vector_type(8))) short bf16x8;
typedef __attribute__((ext_vector_type(4))) short bf16x4;
typedef __attribute__((ext_vector_type(4))) float f32x4;

__device__ __forceinline__ float bf2f(u16 u) {
    return __uint_as_float(((u32)u) << 16);
}
__device__ __forceinline__ u16 f2bf(float f) {
    __hip_bfloat16 h = __float2bfloat16(f);
    return *reinterpret_cast<u16*>(&h);
}

typedef __attribute__((address_space(1))) const u32 gu32;
typedef __attribute__((address_space(3))) u32 lu32;
__device__ __forceinline__ void gl_lds16(const void* g, void* l) {
    // async global->LDS, 16B/lane, dest = wave-uniform base + lane*16
    __builtin_amdgcn_global_load_lds((gu32*)g, (lu32*)l, 16, 0, 0);
}

__device__ __forceinline__ void barrier_c() {
    asm volatile("" ::: "memory");
    __builtin_amdgcn_s_barrier();
    asm volatile("" ::: "memory");
}

// ---------------- fp32->bf16 elementwise ----------------
__global__ __launch_bounds__(256) void cvt1_kernel(const float* __restrict__ s,
                                                   u16* __restrict__ d) {
    int i = (blockIdx.x * 256 + threadIdx.x) * 4;
    float4 v = *(const float4*)(s + i);
    u16 o0 = f2bf(v.x), o1 = f2bf(v.y), o2 = f2bf(v.z), o3 = f2bf(v.w);
    d[i] = o0; d[i+1] = o1; d[i+2] = o2; d[i+3] = o3;
}

// ---------------- transpose + convert: src fp32 [K][N] -> dst bf16 [N][K] ----
__device__ __forceinline__ void trcvt_body(const float* __restrict__ src,
                                           u16* __restrict__ dst, int K, int N,
                                           int n0, int k0) {
    __shared__ u16 tile[64][65];
    int t = threadIdx.x;
    int c = t & 63, r4 = t >> 6;
#pragma unroll
    for (int i = 0; i < 16; i++) {
        int r = i * 4 + r4;
        tile[c][r] = f2bf(src[(size_t)(k0 + r) * N + n0 + c]);
    }
    __syncthreads();
#pragma unroll
    for (int i = 0; i < 16; i++) {
        int rr = i * 4 + r4;
        dst[(size_t)(n0 + rr) * K + k0 + c] = tile[rr][c];
    }
}

struct TP { const float* src[8]; u16* dst[8]; };
__global__ __launch_bounds__(256) void trcvt8_kernel(TP tp) {
    trcvt_body(tp.src[blockIdx.z], tp.dst[blockIdx.z], D_, D_,
               blockIdx.x * 64, blockIdx.y * 64);
}

// both FFN weight transposes in one launch: bid<1024 -> ff_w1 (K=D_,N=F_),
// else ff_w2 (K=F_,N=D_). Saves a kernel launch.
__global__ __launch_bounds__(256) void trcvt_ff_kernel(const float* __restrict__ w1,
                                                       u16* __restrict__ o1,
                                                       const float* __restrict__ w2,
                                                       u16* __restrict__ o2) {
    int bid = blockIdx.x;
    if (bid < 1024) {
        int bx = bid & 63, by = bid >> 6;          // x < F_/64=64, y < D_/64=16
        trcvt_body(w1, o1, D_, F_, bx * 64, by * 64);
    } else {
        int j = bid - 1024;
        int bx = j & 15, by = j >> 4;              // x < D_/64=16, y < F_/64=64
        trcvt_body(w2, o2, F_, D_, bx * 64, by * 64);
    }
}

// ---------------- mask block classify: 0=all-drop, 1=mixed, 2=all-keep ------
// z = 0: self mask -> bm0 ; z = 1: cross mask -> bm1 (one launch).
__global__ __launch_bounds__(256) void mask_reduce2_kernel(const int* __restrict__ m0,
                                                           const int* __restrict__ m1,
                                                           unsigned char* __restrict__ bm0,
                                                           unsigned char* __restrict__ bm1) {
    const int* mask = blockIdx.z ? m1 : m0;
    unsigned char* bmask = blockIdx.z ? bm1 : bm0;
    int t = threadIdx.x;
    int qb = blockIdx.x >> 4, kb = blockIdx.x & 15, b = blockIdx.y;
    bool all1 = true, any1 = false;
#pragma unroll
    for (int i = 0; i < 16; i++) {
        int e = t + i * 256;
        int r = e >> 6, c = e & 63;
        int v = mask[((size_t)(b * S_ + qb * 64 + r)) * S_ + kb * 64 + c];
        all1 = all1 && (v != 0);
        any1 = any1 || (v != 0);
    }
    unsigned long long ba = __ballot(all1), bn = __ballot(any1);
    __shared__ unsigned long long sa[4], sn[4];
    if ((t & 63) == 0) { sa[t >> 6] = ba; sn[t >> 6] = bn; }
    __syncthreads();
    if (t == 0) {
        bool A = ((sa[0] & sa[1] & sa[2] & sa[3]) == ~0ull);
        bool Y = ((sn[0] | sn[1] | sn[2] | sn[3]) != 0ull);
        bmask[b * 256 + blockIdx.x] = A ? 2 : (Y ? 1 : 0);
    }
}

// ---------------- LayerNorm ----------------
template<bool COPY>
__global__ __launch_bounds__(256) void ln_kernel(const float* __restrict__ xin,
                                                 const float* __restrict__ g,
                                                 const float* __restrict__ bta,
                                                 float* xcur,
                                                 u16* __restrict__ hout) {
    int row = blockIdx.x;
    int t = threadIdx.x;
    size_t base = (size_t)row * D_;
    float v[4];
#pragma unroll
    for (int i = 0; i < 4; i++) v[i] = xin[base + t + i * 256];
    float s  = v[0] + v[1] + v[2] + v[3];
    float s2 = v[0]*v[0] + v[1]*v[1] + v[2]*v[2] + v[3]*v[3];
#pragma unroll
    for (int m = 1; m < 64; m <<= 1) {
        s  += __shfl_xor(s, m);
        s2 += __shfl_xor(s2, m);
    }
    __shared__ float red[8];
    int wave = t >> 6;
    if ((t & 63) == 0) { red[wave*2] = s; red[wave*2+1] = s2; }
    __syncthreads();
    float fs  = red[0] + red[2] + red[4] + red[6];
    float fs2 = red[1] + red[3] + red[5] + red[7];
    float mu  = fs * (1.0f / D_);
    float var = fs2 * (1.0f / D_) - mu * mu;
    float rs  = rsqrtf(var + 1e-5f);
#pragma unroll
    for (int i = 0; i < 4; i++) {
        int c = t + i * 256;
        float x = v[i];
        if (COPY) xcur[base + c] = x;
        hout[base + c] = f2bf((x - mu) * rs * g[c] + bta[c]);
    }
}

// ---------------- GEMM: C[M,N] = act(A[M,K] @ Bt[N,K]^T + bias [+ res]) -----
// BK=64, XOR-8 chunk swizzle, single-barrier double-buffered K-loop.
// XCD-aware chunked block swizzle (T1): bijective since all grids %8 == 0.
struct Bias3 { const float* b0; const float* b1; const float* b2; int n1; int n2; };

__device__ __forceinline__ float bias_at(const Bias3& bs, int c) {
    const float* p; int o;
    if (c < bs.n1)      { p = bs.b0; o = c; }
    else if (c < bs.n2) { p = bs.b1; o = c - bs.n1; }
    else                { p = bs.b2; o = c - bs.n2; }
    return p[o];
}

// OUT_MODE: 0 = bf16 out; 1 = bf16 out + relu; 2 = fp32 out + fp32 residual;
//           3 = fp32 raw partial (no bias, no res) -- for split-K;
//           4 = bf16 out with key-permuted column within each 64-block
//               (sigma: 32m+16h+4q+r -> 32m+8q+4h+r) for attn PV b128 reads.
// BIAS_ROW: bias indexed by output row (m) instead of col (n).
template<int BM, int BN, int OUT_MODE, bool BIAS_ROW>
__device__ __forceinline__ void gemm128_body(const u16* __restrict__ A,
                                             const u16* __restrict__ Bt,
                                             Bias3 bias,
                                             const float* res,
                                             void* out,
                                             int M, int N, int K,
                                             int lda, int ldb) {
    constexpr int MT = (BM == 64) ? 4 : (BN == 64 ? 2 : 4);
    constexpr int NT = (BN == 64) ? 4 : (BM == 64 ? 2 : 4);
    __shared__ u16 As[2][BM * 64];
    __shared__ u16 Bs[2][BN * 64];
    int t = threadIdx.x;
    // XCD chunk swizzle over the (x,y) grid slice
    int nx = gridDim.x;
    int nwg = nx * gridDim.y;
    int bid = blockIdx.y * nx + blockIdx.x;
    int swz = (bid & 7) * (nwg >> 3) + (bid >> 3);
    int m0 = (swz / nx) * BM, n0 = (swz % nx) * BN;
    int w = t >> 6, lane = t & 63, quad = lane >> 4, l16 = lane & 15;
    int wm, wn;
    if (BM == 128 && BN == 128) { wm = (w >> 1) * 64; wn = (w & 1) * 64; }
    else if (BN == 64)          { wm = w * 32;        wn = 0; }
    else                        { wm = 0;             wn = w * 32; }

    f32x4 acc[MT][NT] = {};
    int sr = lane >> 3;                      // staging row within 8-row group
    int gc = ((lane & 7) ^ sr) * 8;          // swizzled source chunk (u16)
    int x7 = l16 & 7;                        // frag-read swizzle key
    const u16* gA = A + (size_t)m0 * lda;
    const u16* gB = Bt + (size_t)n0 * ldb;

    auto stage = [&](int k0, int buf) {
#pragma unroll
        for (int j = w; j < BM / 8; j += 4)
            gl_lds16(gA + (size_t)(j * 8 + sr) * lda + k0 + gc, &As[buf][j * 512]);
#pragma unroll
        for (int j = w; j < BN / 8; j += 4)
            gl_lds16(gB + (size_t)(j * 8 + sr) * ldb + k0 + gc, &Bs[buf][j * 512]);
    };

    stage(0, 0);
    int cur = 0;
    for (int k0 = 0; k0 < K; k0 += 64) {
        __syncthreads();   // drains DMA for cur (issued a full compute phase ago)
        if (k0 + 64 < K) stage(k0 + 64, cur ^ 1);   // DMA overlaps compute

#pragma unroll
        for (int s = 0; s < 2; s++) {
            bf16x8 af[MT], bfr[NT];
            int cp = ((s * 4 + quad) ^ x7) * 8;
#pragma unroll
            for (int mt = 0; mt < MT; mt++)
                af[mt] = *(const bf16x8*)&As[cur][(wm + mt * 16 + l16) * 64 + cp];
#pragma unroll
            for (int nt = 0; nt < NT; nt++)
                bfr[nt] = *(const bf16x8*)&Bs[cur][(wn + nt * 16 + l16) * 64 + cp];
#pragma unroll
            for (int mt = 0; mt < MT; mt++)
#pragma unroll
                for (int nt = 0; nt < NT; nt++)
                    acc[mt][nt] = __builtin_amdgcn_mfma_f32_16x16x32_bf16(af[mt], bfr[nt], acc[mt][nt], 0, 0, 0);
        }
        cur ^= 1;
    }

#pragma unroll
    for (int nt = 0; nt < NT; nt++) {
        int col = n0 + wn + nt * 16 + l16;
        float bc = (OUT_MODE == 3) ? 0.f : (BIAS_ROW ? 0.f : bias_at(bias, col));
#pragma unroll
        for (int mt = 0; mt < MT; mt++) {
#pragma unroll
            for (int r = 0; r < 4; r++) {
                int row = m0 + wm + mt * 16 + quad * 4 + r;
                float v = acc[mt][nt][r] + bc;
                if (OUT_MODE != 3 && BIAS_ROW) v += bias_at(bias, row);
                if (OUT_MODE == 1) v = fmaxf(v, 0.f);
                if (OUT_MODE == 2) {
                    v += res[(size_t)row * N + col];
                    ((float*)out)[(size_t)row * N + col] = v;
                } else if (OUT_MODE == 3) {
                    ((float*)out)[(size_t)row * N + col] = v;
                } else if (OUT_MODE == 4) {
                    int pc = (col & ~63) | (col & 32) | ((col & 0xC) << 1) |
                             ((col & 0x10) >> 2) | (col & 3);
                    ((u16*)out)[(size_t)row * N + pc] = f2bf(v);
                } else {
                    ((u16*)out)[(size_t)row * N + col] = f2bf(v);
                }
            }
        }
    }
}

template<int BM, int BN, int OUT_MODE, bool BIAS_ROW>
__global__ __launch_bounds__(256) void gemm128_kernel(const u16* __restrict__ A,
                                                      const u16* __restrict__ Bt,
                                                      Bias3 bias,
                                                      const float* res,
                                                      void* out,
                                                      int M, int N, int K) {
    gemm128_body<BM, BN, OUT_MODE, BIAS_ROW>(A, Bt, bias, res, out, M, N, K, K, K);
}

// split-K=2: z selects K-half; both halves write fp32 partials (reduced later).
// 128x128 tile, grid (8,32,2)=512 blocks -> 2/CU. Measured 47.4 us (round 5);
// the 8-phase 256x128 port regressed (50.0, round 6): NT=2 phases too fine.
__global__ __launch_bounds__(256) void gemm128_splitk2_kernel(const u16* __restrict__ A,
                                                              const u16* __restrict__ Bt,
                                                              float* __restrict__ p0,
                                                              float* __restrict__ p1,
                                                              int M, int N, int Kh, int ld) {
    int z = blockIdx.z;
    Bias3 dummy = { nullptr, nullptr, nullptr, 1 << 30, 1 << 30 };
    gemm128_body<128, 128, 3, false>(A + z * Kh, Bt + z * Kh, dummy, nullptr,
                                     z ? (void*)p1 : (void*)p0, M, N, Kh, ld, ld);
}

// d_out = p0 + p1 + bias[col] + res  (fp32)
__global__ __launch_bounds__(256) void ffn2_reduce_kernel(const float* __restrict__ p0,
                                                          const float* __restrict__ p1,
                                                          const float* __restrict__ b2,
                                                          const float* __restrict__ res,
                                                          float* __restrict__ out) {
    int i = (blockIdx.x * 256 + threadIdx.x) * 4;
    int col = i & (D_ - 1);
    float4 a = *(const float4*)(p0 + i);
    float4 b = *(const float4*)(p1 + i);
    float4 r = *(const float4*)(res + i);
    float4 bb = *(const float4*)(b2 + col);
    float4 o;
    o.x = a.x + b.x + r.x + bb.x;
    o.y = a.y + b.y + r.y + bb.y;
    o.z = a.z + b.z + r.z + bb.z;
    o.w = a.w + b.w + r.w + bb.w;
    *(float4*)(out + i) = o;
}

// two independent same-shape GEMMs in one launch (z selects).
// 128x128 tile (32 MFMA/K-step/wave), grid (8,32,2)=512 blocks -> 2/CU.
struct Pair2 {
    const u16* A0; const u16* A1;
    const u16* B0; const u16* B1;
    const float* b0; const float* b1;
    u16* o0; u16* o1;
};
__global__ __launch_bounds__(256) void gemm128_pairqk_kernel(Pair2 p, int M, int N, int K) {
    int z = blockIdx.z;
    const u16* A  = z ? p.A1 : p.A0;
    const u16* Bt = z ? p.B1 : p.B0;
    const float* bb = z ? p.b1 : p.b0;
    u16* o = z ? p.o1 : p.o0;
    Bias3 bs = { bb, bb, bb, 1 << 30, 1 << 30 };
    gemm128_body<128, 128, 0, false>(A, Bt, bs, nullptr, o, M, N, K, K, K);
}

// ---------------- 8-phase 256x256 GEMM (T3+T4+T5), bias+relu, bf16 out -----
// 512 threads = 8 waves (2M x 4N), per-wave 128x64 output, BK=64.
// LDS 128 KB flat: loop = As|Bs (2 bufs x 2 halves x [128][64] each, XOR-8
// chunk swizzle); epilogue REUSES it as the 256x256 bf16 output tile.
// Counted vmcnt(8) at tile boundaries (never 0 except last iter); raw s_barrier.
// Ledger: 8 load-instrs/wave/tile; at iter t boundary outstanding is a subset
// of {S(t), S(t+1)} -> vmcnt(8) guarantees S(t) landed. stage(t+2) targets
// buf[t&1] whose reads this iter are complete (lgkmcnt(0)+barrier: A after P1,
// B after P2). Accumulation order identical to gemm128 (kk0 then kk1 per tile).
// Epilogue: acc -> LDS (quad-XOR slot swizzle) -> coalesced dwordx4 stores.
// Only used where grid >= 256 at 256^2 tile (FFN1) — smaller-N shapes regress.
__global__ __launch_bounds__(512) void gemm8p_kernel(const u16* __restrict__ A,
                                                     const u16* __restrict__ Bt,
                                                     const float* __restrict__ bias,
                                                     u16* __restrict__ out,
                                                     int M, int N, int K) {
    __shared__ u16 smem[65536];          // 128 KB
    u16* Asb = smem;                     // [(buf*2+half)*8192]
    u16* Bsb = smem + 32768;
    int t = threadIdx.x;
    int w = t >> 6, lane = t & 63, quad = lane >> 4, l16 = lane & 15;
    int wr = w >> 2, wc = w & 3;
    int nx = gridDim.x;
    int nwg = nx * gridDim.y;
    int bid = blockIdx.y * nx + blockIdx.x;
    int swz = (bid & 7) * (nwg >> 3) + (bid >> 3);
    int n0 = (swz % nx) * 256, m0 = (swz / nx) * 256;
    int sr = lane >> 3, gc = ((lane & 7) ^ sr) * 8;
    const u16* gA = A + (size_t)m0 * K;
    const u16* gB = Bt + (size_t)n0 * K;

    f32x4 acc[8][4] = {};
    int ntt = K >> 6;

    auto stageA = [&](int ti) {
        int buf = ti & 1, k0 = ti << 6;
        gl_lds16(gA + (size_t)(w * 8 + sr) * K + k0 + gc,             Asb + buf * 16384 + w * 512);
        gl_lds16(gA + (size_t)((w + 8) * 8 + sr) * K + k0 + gc,       Asb + buf * 16384 + (w + 8) * 512);
        gl_lds16(gA + (size_t)(128 + w * 8 + sr) * K + k0 + gc,       Asb + buf * 16384 + 8192 + w * 512);
        gl_lds16(gA + (size_t)(128 + (w + 8) * 8 + sr) * K + k0 + gc, Asb + buf * 16384 + 8192 + (w + 8) * 512);
    };
    auto stageB = [&](int ti) {
        int buf = ti & 1, k0 = ti << 6;
        gl_lds16(gB + (size_t)(w * 8 + sr) * K + k0 + gc,             Bsb + buf * 16384 + w * 512);
        gl_lds16(gB + (size_t)((w + 8) * 8 + sr) * K + k0 + gc,       Bsb + buf * 16384 + (w + 8) * 512);
        gl_lds16(gB + (size_t)(128 + w * 8 + sr) * K + k0 + gc,       Bsb + buf * 16384 + 8192 + w * 512);
        gl_lds16(gB + (size_t)(128 + (w + 8) * 8 + sr) * K + k0 + gc, Bsb + buf * 16384 + 8192 + (w + 8) * 512);
    };

    stageA(0); stageB(0);
    stageA(1); stageB(1);

    for (int ti = 0; ti < ntt; ++ti) {
        int buf = ti & 1;
        if (ti == ntt - 1) asm volatile("s_waitcnt vmcnt(0)" ::: "memory");
        else               asm volatile("s_waitcnt vmcnt(8)" ::: "memory");
        __builtin_amdgcn_sched_barrier(0);
        barrier_c();
        const u16* Ah = Asb + buf * 16384 + wr * 8192;
        const u16* Bh = Bsb + buf * 16384 + (wc >> 1) * 8192;
        int br0 = (wc & 1) * 64;
        bf16x8 a0[8], a1[8], b0[4], b1[4];

        // P0: read A kk0 (8) + B kk0 (4); MFMA mt0-3 x kk0
#pragma unroll
        for (int mt = 0; mt < 8; mt++) {
            int lr = mt * 16 + l16;
            a0[mt] = *(const bf16x8*)&Ah[lr * 64 + ((quad ^ (lr & 7)) * 8)];
        }
#pragma unroll
        for (int nt = 0; nt < 4; nt++) {
            int lr = br0 + nt * 16 + l16;
            b0[nt] = *(const bf16x8*)&Bh[lr * 64 + ((quad ^ (lr & 7)) * 8)];
        }
        __builtin_amdgcn_s_setprio(1);
#pragma unroll
        for (int mt = 0; mt < 4; mt++)
#pragma unroll
            for (int nt = 0; nt < 4; nt++)
                acc[mt][nt] = __builtin_amdgcn_mfma_f32_16x16x32_bf16(a0[mt], b0[nt], acc[mt][nt], 0, 0, 0);
        __builtin_amdgcn_s_setprio(0);
        barrier_c();

        // P1: read A kk1 (8); MFMA mt4-7 x kk0
#pragma unroll
        for (int mt = 0; mt < 8; mt++) {
            int lr = mt * 16 + l16;
            a1[mt] = *(const bf16x8*)&Ah[lr * 64 + (((4 + quad) ^ (lr & 7)) * 8)];
        }
        __builtin_amdgcn_s_setprio(1);
#pragma unroll
        for (int mt = 4; mt < 8; mt++)
#pragma unroll
            for (int nt = 0; nt < 4; nt++)
                acc[mt][nt] = __builtin_amdgcn_mfma_f32_16x16x32_bf16(a0[mt], b0[nt], acc[mt][nt], 0, 0, 0);
        __builtin_amdgcn_s_setprio(0);
        asm volatile("s_waitcnt lgkmcnt(0)" ::: "memory");   // all A-reads landed
        __builtin_amdgcn_sched_barrier(0);
        barrier_c();

        // P2: read B kk1 (4) + stage A(ti+2) into just-freed A slots; MFMA mt0-3 x kk1
#pragma unroll
        for (int nt = 0; nt < 4; nt++) {
            int lr = br0 + nt * 16 + l16;
            b1[nt] = *(const bf16x8*)&Bh[lr * 64 + (((4 + quad) ^ (lr & 7)) * 8)];
        }
        if (ti + 2 < ntt) stageA(ti + 2);
        __builtin_amdgcn_s_setprio(1);
#pragma unroll
        for (int mt = 0; mt < 4; mt++)
#pragma unroll
            for (int nt = 0; nt < 4; nt++)
                acc[mt][nt] = __builtin_amdgcn_mfma_f32_16x16x32_bf16(a1[mt], b1[nt], acc[mt][nt], 0, 0, 0);
        __builtin_amdgcn_s_setprio(0);
        asm volatile("s_waitcnt lgkmcnt(0)" ::: "memory");   // all B-reads landed
        __builtin_amdgcn_sched_barrier(0);
        barrier_c();

        // P3: stage B(ti+2); MFMA mt4-7 x kk1
        if (ti + 2 < ntt) stageB(ti + 2);
        __builtin_amdgcn_s_setprio(1);
#pragma unroll
        for (int mt = 4; mt < 8; mt++)
#pragma unroll
            for (int nt = 0; nt < 4; nt++)
                acc[mt][nt] = __builtin_amdgcn_mfma_f32_16x16x32_bf16(a1[mt], b1[nt], acc[mt][nt], 0, 0, 0);
        __builtin_amdgcn_s_setprio(0);
        // next iteration's vmcnt + barrier closes the tile
    }

    // ---- epilogue: bias+relu -> LDS (swizzled) -> coalesced global stores ----
    barrier_c();                       // all LDS reads done; repurpose smem
    u16* ot = smem;                    // logical [256][256] u16, col ^ (quad<<4)
#pragma unroll
    for (int nt = 0; nt < 4; nt++) {
        float bc = bias[n0 + wc * 64 + nt * 16 + l16];
        int csw = wc * 64 + ((nt ^ quad) * 16) + l16;   // swizzled slot
#pragma unroll
        for (int mt = 0; mt < 8; mt++) {
#pragma unroll
            for (int r = 0; r < 4; r++) {
                int row = wr * 128 + mt * 16 + quad * 4 + r;
                ot[row * 256 + csw] = f2bf(fmaxf(acc[mt][nt][r] + bc, 0.f));
            }
        }
    }
    barrier_c();                       // all writes visible
    int tr = t >> 5, tc = t & 31;
#pragma unroll
    for (int ps = 0; ps < 16; ps++) {
        int row = ps * 16 + tr;
        int qd = (row >> 2) & 3;
        int csw = (tc * 8) ^ (qd << 4);
        bf16x8 v = *(const bf16x8*)&ot[row * 256 + csw];
        *(bf16x8*)&out[(size_t)(m0 + row) * N + n0 + tc * 8] = v;
    }
}

// ---------------- Flash attention ----------------
// One q-tile per block, grid.x = 16 (1024 blocks -> 4 resident/CU at 32 KB LDS).
// Per-64-key double-buffered staging. S^T = K·Q^T via MFMA (operand swap) ->
// exp outputs land directly in the PV A-fragment (k-slot relabeling). V^T is
// stored with sigma-permuted keys (by the V-GEMM epilogue) so the PV B-fragment
// is ONE conflict-free XOR-8 ds_read_b128.
// Row-sum via MFMA with ones. No running max: scores bounded; clamp.
// Q pre-scaled by 0.125*log2e -> p = exp2(s) directly (saves a VALU mul/elem).
__global__ __launch_bounds__(256) void attn_kernel(const u16* __restrict__ Q, int ldq,
                                                   const u16* __restrict__ Kb, int ldk,
                                                   const u16* __restrict__ Vt,
                                                   const int* __restrict__ mask,
                                                   const unsigned char* __restrict__ bmask,
                                                   u16* __restrict__ ctx) {
    __shared__ u16 Ks[2][64 * 64];   // [buf][key][dh], XOR-8 swizzled
    __shared__ u16 Vs[2][64 * 64];   // [buf][dh][perm-key], XOR-8 swizzled
    int t = threadIdx.x;
    int b = blockIdx.z, hh = blockIdx.y, qt = blockIdx.x;
    int w = t >> 6, lane = t & 63, quad = lane >> 4, l16 = lane & 15;
    int hoff = hh * DH_;

    bf16x8 ones8;
#pragma unroll
    for (int j = 0; j < 8; j++) ones8[j] = (short)0x3F80;  // bf16 1.0

    // Q fragments (B-operand for S^T), scaled 1/8 * log2(e)
    bf16x8 qf[2];
    int qrow = qt * 64 + w * 16 + l16;
#pragma unroll
    for (int kk = 0; kk < 2; kk++) {
        bf16x8 v = *(const bf16x8*)(Q + (size_t)(b * S_ + qrow) * ldq + hoff + kk * 32 + quad * 8);
#pragma unroll
        for (int j = 0; j < 8; j++)
            v[j] = (short)f2bf(bf2f((u16)v[j]) * 0.1803368801f);
        qf[kk] = v;
    }

    f32x4 oacc[4] = {};
    f32x4 lacc = {};

    // block-mask bitfields over 16 64-key chunks (wave-uniform)
    unsigned nz = 0, mx = 0;
    for (int c = 0; c < 16; c++) {
        int v = bmask ? (int)bmask[(b * 16 + qt) * 16 + c] : 1;
        if (v)      nz |= 1u << c;
        if (v == 1) mx |= 1u << c;
    }

    int sr = lane >> 3;                  // staging row within 8-row group
    int gc = ((lane & 7) ^ sr) * 8;      // swizzled source chunk (u16)

    auto stage64 = [&](int c, int buf) {
        int k0 = c * 64;
        for (int j = w; j < 8; j += 4) {
            gl_lds16(Kb + (size_t)(b * S_ + k0 + j * 8 + sr) * ldk + hoff + gc, &Ks[buf][j * 512]);
            gl_lds16(Vt + (size_t)(hoff + j * 8 + sr) * (B_ * S_) + b * S_ + k0 + gc, &Vs[buf][j * 512]);
        }
    };

    unsigned rem = nz;
    int c = rem ? __builtin_ctz(rem) : -1;
    if (c >= 0) stage64(c, 0);
    int cur = 0;

    while (c >= 0) {
        rem &= rem - 1;
        int nc = rem ? __builtin_ctz(rem) : -1;
        __syncthreads();                     // drain staging of cur; readers of cur^1 done
        if (nc >= 0) stage64(nc, cur ^ 1);   // DMA overlaps compute below

        int k0c = c * 64;
        bool mixed = (mx >> c) & 1u;
        const u16* KsT = Ks[cur];
        const u16* VsT = Vs[cur];

        // S^T tile: lane holds S[q = qrow][key = k0c+nt*16+quad*4+r]
        float p[4][4];
#pragma unroll
        for (int nt = 0; nt < 4; nt++) {
            f32x4 sacc = {};
            int krow = nt * 16 + l16;
            __builtin_amdgcn_s_setprio(1);
#pragma unroll
            for (int kk = 0; kk < 2; kk++) {
                int cp = ((kk * 4 + quad) ^ (krow & 7)) * 8;
                bf16x8 kf = *(const bf16x8*)&KsT[krow * 64 + cp];
                sacc = __builtin_amdgcn_mfma_f32_16x16x32_bf16(kf, qf[kk], sacc, 0, 0, 0);
            }
            __builtin_amdgcn_s_setprio(0);
#pragma unroll
            for (int r = 0; r < 4; r++) {
                float sv = sacc[r];
                if (mixed) {
                    int kc = k0c + nt * 16 + quad * 4 + r;
                    if (mask[(size_t)(b * S_ + qrow) * S_ + kc] == 0) sv = -1e9f;
                }
                p[nt][r] = exp2f(fminf(sv, 28.8539008f));
            }
        }

        // PV + rowsum directly from registers (k-slot relabeled x32 MFMA).
        // V-fragment: single b128 read thanks to sigma-permuted Vs layout.
#pragma unroll
        for (int mp = 0; mp < 2; mp++) {
            bf16x8 af;
#pragma unroll
            for (int r = 0; r < 4; r++) {
                af[r]     = (short)f2bf(p[2 * mp][r]);
                af[4 + r] = (short)f2bf(p[2 * mp + 1][r]);
            }
            __builtin_amdgcn_s_setprio(1);
            lacc = __builtin_amdgcn_mfma_f32_16x16x32_bf16(af, ones8, lacc, 0, 0, 0);
#pragma unroll
            for (int dt = 0; dt < 4; dt++) {
                int vrow = dt * 16 + l16;
                int ch = (mp * 4 + quad) ^ (vrow & 7);
                bf16x8 vf = *(const bf16x8*)&VsT[vrow * 64 + ch * 8];
                oacc[dt] = __builtin_amdgcn_mfma_f32_16x16x32_bf16(af, vf, oacc[dt], 0, 0, 0);
            }
            __builtin_amdgcn_s_setprio(0);
        }
        c = nc;
        cur ^= 1;
    }

#pragma unroll
    for (int dt = 0; dt < 4; dt++)
#pragma unroll
        for (int r = 0; r < 4; r++) {
            int qq = qt * 64 + w * 16 + quad * 4 + r;
            float l = lacc[r];
            float inv = l > 0.f ? 1.f / l : 0.f;
            ctx[(size_t)(b * S_ + qq) * D_ + hoff + dt * 16 + l16] = f2bf(oacc[dt][r] * inv);
        }
}

extern "C" void kernel_launch(void* const* d_in, const int* in_sizes, int n_in,
                              void* d_out, int out_size, void* d_ws, size_t ws_size,
                              hipStream_t stream) {
    const float* x     = (const float*)d_in[0];
    const float* srcx  = (const float*)d_in[1];
    const int*   mask  = (const int*)d_in[2];
    const int*   smask = (const int*)d_in[3];
    const float* ln1g = (const float*)d_in[4],  *ln1b = (const float*)d_in[5];
    const float* ln2g = (const float*)d_in[6],  *ln2b = (const float*)d_in[7];
    const float* ln3g = (const float*)d_in[8],  *ln3b = (const float*)d_in[9];
    const float* sa_wq = (const float*)d_in[10], *sa_bq = (const float*)d_in[11];
    const float* sa_wk = (const float*)d_in[12], *sa_bk = (const float*)d_in[13];
    const float* sa_wv = (const float*)d_in[14], *sa_bv = (const float*)d_in[15];
    const float* sa_wo = (const float*)d_in[16], *sa_bo = (const float*)d_in[17];
    const float* ca_wq = (const float*)d_in[18], *ca_bq = (const float*)d_in[19];
    const float* ca_wk = (const float*)d_in[20], *ca_bk = (const float*)d_in[21];
    const float* ca_wv = (const float*)d_in[22], *ca_bv = (const float*)d_in[23];
    const float* ca_wo = (const float*)d_in[24], *ca_bo = (const float*)d_in[25];
    const float* ff_w1 = (const float*)d_in[26], *ff_b1 = (const float*)d_in[27];
    const float* ff_w2 = (const float*)d_in[28], *ff_b2 = (const float*)d_in[29];

    char* ws = (char*)d_ws;
    const size_t MB = 1ull << 20;
    const size_t DD = (size_t)D_ * D_;
    float* xcur = (float*)ws;                  // 16 MB fp32 residual
    u16* h     = (u16*)(ws + 16 * MB);         // 8 MB LN output
    u16* qk    = (u16*)(ws + 24 * MB);         // self: [4096][2048] 16 MB
    u16* qb    = (u16*)(ws + 24 * MB);         // cross Q [4096][1024] 8 MB
    u16* kbuf  = (u16*)(ws + 32 * MB);         // cross K 8 MB
    u16* vt    = (u16*)(ws + 40 * MB);         // V^T [1024][4096] 8 MB (perm keys)
    u16* ctx   = (u16*)(ws + 48 * MB);         // 8 MB
    u16* ff    = (u16*)(ws + 24 * MB);         // ffn [4096][4096] 32 MB (reuse)
    u16* sxb   = (u16*)(ws + 56 * MB);         // bf16 src_x 8 MB
    u16* wqk_s = (u16*)(ws + 64 * MB);         // [2048][1024] 4 MB
    u16* wv_s  = (u16*)(ws + 68 * MB);
    u16* wo_s  = (u16*)(ws + 70 * MB);
    u16* wq_c  = (u16*)(ws + 72 * MB);
    u16* wk_c  = (u16*)(ws + 74 * MB);
    u16* wv_c  = (u16*)(ws + 76 * MB);
    u16* wo_c  = (u16*)(ws + 78 * MB);
    u16* wff1  = (u16*)(ws + 80 * MB);         // [4096][1024] 8 MB
    u16* wff2  = (u16*)(ws + 88 * MB);         // [1024][4096] 8 MB
    // FFN2 split-K partials: these regions are dead by FFN time
    // (sxb + staged self/cross weights + wff1 all consumed).
    float* fp0 = (float*)(ws + 56 * MB);       // 16 MB fp32 partial (k 0..2047)
    float* fp1 = (float*)(ws + 72 * MB);       // 16 MB fp32 partial (k 2048..4095)
    unsigned char* bm_self = nullptr, *bm_cross = nullptr;
    if (ws_size >= 96 * MB + 8192) {           // constant across calls -> graph-safe
        bm_self  = (unsigned char*)(ws + ws_size - 8192);
        bm_cross = bm_self + 4096;
    }

    dim3 blk(256);

    // ---- setup: weight transposes, src_x convert, mask classify ----
    TP tp = {{sa_wq, sa_wk, sa_wv, sa_wo, ca_wq, ca_wk, ca_wv, ca_wo},
             {wqk_s, wqk_s + DD, wv_s, wo_s, wq_c, wk_c, wv_c, wo_c}};
    trcvt8_kernel<<<dim3(16, 16, 8), blk, 0, stream>>>(tp);
    trcvt_ff_kernel<<<dim3(2048), blk, 0, stream>>>(ff_w1, wff1, ff_w2, wff2);
    cvt1_kernel<<<B_ * S_ * D_ / 1024, blk, 0, stream>>>(srcx, sxb);
    if (bm_self) {
        mask_reduce2_kernel<<<dim3(256, B_, 2), blk, 0, stream>>>(mask, smask, bm_self, bm_cross);
    }

    Bias3 bqk = { sa_bq, sa_bk, sa_bk, 1024, 2048 };
    Bias3 bsv = { sa_bv, sa_bv, sa_bv, 1 << 30, 1 << 30 };
    Bias3 bso = { sa_bo, sa_bo, sa_bo, 1 << 30, 1 << 30 };
    Bias3 bcv = { ca_bv, ca_bv, ca_bv, 1 << 30, 1 << 30 };
    Bias3 bco = { ca_bo, ca_bo, ca_bo, 1 << 30, 1 << 30 };

    // ---- self attention ----
    ln_kernel<true><<<B_ * S_, blk, 0, stream>>>(x, ln1g, ln1b, xcur, h);
    gemm128_kernel<128,128,0,false><<<dim3(16, 32), blk, 0, stream>>>(h, wqk_s, bqk, nullptr, qk, 4096, 2048, 1024);
    gemm128_kernel<64,128,4,true><<<dim3(32, 16), blk, 0, stream>>>(wv_s, h, bsv, nullptr, vt, 1024, 4096, 1024);
    attn_kernel<<<dim3(16, H_, B_), blk, 0, stream>>>(qk, 2048, qk + 1024, 2048, vt, mask, bm_self, ctx);
    gemm128_kernel<128,64,2,false><<<dim3(16, 32), blk, 0, stream>>>(ctx, wo_s, bso, xcur, xcur, 4096, 1024, 1024);

    // ---- cross attention ----
    ln_kernel<false><<<B_ * S_, blk, 0, stream>>>(xcur, ln2g, ln2b, nullptr, h);
    {
        Pair2 pqk = { h, sxb, wq_c, wk_c, ca_bq, ca_bk, qb, kbuf };
        gemm128_pairqk_kernel<<<dim3(8, 32, 2), blk, 0, stream>>>(pqk, 4096, 1024, 1024);
    }
    gemm128_kernel<64,128,4,true><<<dim3(32, 16), blk, 0, stream>>>(wv_c, sxb, bcv, nullptr, vt, 1024, 4096, 1024);
    attn_kernel<<<dim3(16, H_, B_), blk, 0, stream>>>(qb, 1024, kbuf, 1024, vt, smask, bm_cross, ctx);
    gemm128_kernel<128,64,2,false><<<dim3(16, 32), blk, 0, stream>>>(ctx, wo_c, bco, xcur, xcur, 4096, 1024, 1024);

    // ---- FFN ----
    ln_kernel<false><<<B_ * S_, blk, 0, stream>>>(xcur, ln3g, ln3b, nullptr, h);
    gemm8p_kernel<<<dim3(16, 16), dim3(512), 0, stream>>>(h, wff1, ff_b1, ff, 4096, 4096, 1024);
    // FFN2: 128^2 split-K=2 (measured best structure for this shape, round 5)
    gemm128_splitk2_kernel<<<dim3(8, 32, 2), blk, 0, stream>>>(ff, wff2, fp0, fp1, 4096, 1024, 2048, 4096);
    ffn2_reduce_kernel<<<dim3(B_ * S_ * D_ / 1024), blk, 0, stream>>>(fp0, fp1, ff_b2, xcur, (float*)d_out);
}

// Round 8
// 530.281 us; speedup vs baseline: 1.0162x; 1.0162x over previous
//
#include <hip/hip_runtime.h>
#include <hip/hip_bf16.h>

#define B_ 4
#define S_ 1024
#define D_ 1024
#define H_ 16
#define DH_ 64
#define F_ 4096

typedef unsigned short u16;
typedef unsigned int u32;
typedef __attribute__((ext_vector_type(8))) short bf16x8;
typedef __attribute__((ext_vector_type(4))) short bf16x4;
typedef __attribute__((ext_vector_type(4))) float f32x4;

__device__ __forceinline__ float bf2f(u16 u) {
    return __uint_as_float(((u32)u) << 16);
}
__device__ __forceinline__ u16 f2bf(float f) {
    __hip_bfloat16 h = __float2bfloat16(f);
    return *reinterpret_cast<u16*>(&h);
}

typedef __attribute__((address_space(1))) const u32 gu32;
typedef __attribute__((address_space(3))) u32 lu32;
__device__ __forceinline__ void gl_lds16(const void* g, void* l) {
    // async global->LDS, 16B/lane, dest = wave-uniform base + lane*16
    __builtin_amdgcn_global_load_lds((gu32*)g, (lu32*)l, 16, 0, 0);
}

__device__ __forceinline__ void barrier_c() {
    asm volatile("" ::: "memory");
    __builtin_amdgcn_s_barrier();
    asm volatile("" ::: "memory");
}

// ---------------- fp32->bf16 elementwise ----------------
__global__ __launch_bounds__(256) void cvt1_kernel(const float* __restrict__ s,
                                                   u16* __restrict__ d) {
    int i = (blockIdx.x * 256 + threadIdx.x) * 4;
    float4 v = *(const float4*)(s + i);
    u16 o0 = f2bf(v.x), o1 = f2bf(v.y), o2 = f2bf(v.z), o3 = f2bf(v.w);
    d[i] = o0; d[i+1] = o1; d[i+2] = o2; d[i+3] = o3;
}

// ---------------- transpose + convert: src fp32 [K][N] -> dst bf16 [N][K] ----
__device__ __forceinline__ void trcvt_body(const float* __restrict__ src,
                                           u16* __restrict__ dst, int K, int N,
                                           int n0, int k0) {
    __shared__ u16 tile[64][65];
    int t = threadIdx.x;
    int c = t & 63, r4 = t >> 6;
#pragma unroll
    for (int i = 0; i < 16; i++) {
        int r = i * 4 + r4;
        tile[c][r] = f2bf(src[(size_t)(k0 + r) * N + n0 + c]);
    }
    __syncthreads();
#pragma unroll
    for (int i = 0; i < 16; i++) {
        int rr = i * 4 + r4;
        dst[(size_t)(n0 + rr) * K + k0 + c] = tile[rr][c];
    }
}

__global__ __launch_bounds__(256) void trcvt_kernel(const float* __restrict__ src,
                                                    u16* __restrict__ dst,
                                                    int K, int N) {
    trcvt_body(src, dst, K, N, blockIdx.x * 64, blockIdx.y * 64);
}

struct TP { const float* src[8]; u16* dst[8]; };
__global__ __launch_bounds__(256) void trcvt8_kernel(TP tp) {
    trcvt_body(tp.src[blockIdx.z], tp.dst[blockIdx.z], D_, D_,
               blockIdx.x * 64, blockIdx.y * 64);
}

// ---------------- mask block classify: 0=all-drop, 1=mixed, 2=all-keep ------
__global__ __launch_bounds__(256) void mask_reduce_kernel(const int* __restrict__ mask,
                                                          unsigned char* __restrict__ bmask) {
    int t = threadIdx.x;
    int qb = blockIdx.x >> 4, kb = blockIdx.x & 15, b = blockIdx.y;
    bool all1 = true, any1 = false;
#pragma unroll
    for (int i = 0; i < 16; i++) {
        int e = t + i * 256;
        int r = e >> 6, c = e & 63;
        int v = mask[((size_t)(b * S_ + qb * 64 + r)) * S_ + kb * 64 + c];
        all1 = all1 && (v != 0);
        any1 = any1 || (v != 0);
    }
    unsigned long long ba = __ballot(all1), bn = __ballot(any1);
    __shared__ unsigned long long sa[4], sn[4];
    if ((t & 63) == 0) { sa[t >> 6] = ba; sn[t >> 6] = bn; }
    __syncthreads();
    if (t == 0) {
        bool A = ((sa[0] & sa[1] & sa[2] & sa[3]) == ~0ull);
        bool Y = ((sn[0] | sn[1] | sn[2] | sn[3]) != 0ull);
        bmask[b * 256 + blockIdx.x] = A ? 2 : (Y ? 1 : 0);
    }
}

// ---------------- LayerNorm ----------------
template<bool COPY>
__global__ __launch_bounds__(256) void ln_kernel(const float* __restrict__ xin,
                                                 const float* __restrict__ g,
                                                 const float* __restrict__ bta,
                                                 float* xcur,
                                                 u16* __restrict__ hout) {
    int row = blockIdx.x;
    int t = threadIdx.x;
    size_t base = (size_t)row * D_;
    float v[4];
#pragma unroll
    for (int i = 0; i < 4; i++) v[i] = xin[base + t + i * 256];
    float s  = v[0] + v[1] + v[2] + v[3];
    float s2 = v[0]*v[0] + v[1]*v[1] + v[2]*v[2] + v[3]*v[3];
#pragma unroll
    for (int m = 1; m < 64; m <<= 1) {
        s  += __shfl_xor(s, m);
        s2 += __shfl_xor(s2, m);
    }
    __shared__ float red[8];
    int wave = t >> 6;
    if ((t & 63) == 0) { red[wave*2] = s; red[wave*2+1] = s2; }
    __syncthreads();
    float fs  = red[0] + red[2] + red[4] + red[6];
    float fs2 = red[1] + red[3] + red[5] + red[7];
    float mu  = fs * (1.0f / D_);
    float var = fs2 * (1.0f / D_) - mu * mu;
    float rs  = rsqrtf(var + 1e-5f);
#pragma unroll
    for (int i = 0; i < 4; i++) {
        int c = t + i * 256;
        float x = v[i];
        if (COPY) xcur[base + c] = x;
        hout[base + c] = f2bf((x - mu) * rs * g[c] + bta[c]);
    }
}

// ---------------- GEMM: C[M,N] = act(A[M,K] @ Bt[N,K]^T + bias [+ res]) -----
// BK=64, XOR-8 chunk swizzle, single-barrier double-buffered K-loop.
// XCD-aware chunked block swizzle (T1): bijective since all grids %8 == 0.
struct Bias3 { const float* b0; const float* b1; const float* b2; int n1; int n2; };

__device__ __forceinline__ float bias_at(const Bias3& bs, int c) {
    const float* p; int o;
    if (c < bs.n1)      { p = bs.b0; o = c; }
    else if (c < bs.n2) { p = bs.b1; o = c - bs.n1; }
    else                { p = bs.b2; o = c - bs.n2; }
    return p[o];
}

// OUT_MODE: 0 = bf16 out; 1 = bf16 out + relu; 2 = fp32 out + fp32 residual;
//           3 = fp32 raw partial (no bias, no res) -- for split-K;
//           4 = bf16 out with key-permuted column within each 64-block
//               (sigma: 32m+16h+4q+r -> 32m+8q+4h+r) for attn PV b128 reads.
// BIAS_ROW: bias indexed by output row (m) instead of col (n).
template<int BM, int BN, int OUT_MODE, bool BIAS_ROW>
__device__ __forceinline__ void gemm128_body(const u16* __restrict__ A,
                                             const u16* __restrict__ Bt,
                                             Bias3 bias,
                                             const float* res,
                                             void* out,
                                             int M, int N, int K,
                                             int lda, int ldb) {
    constexpr int MT = (BM == 64) ? 4 : (BN == 64 ? 2 : 4);
    constexpr int NT = (BN == 64) ? 4 : (BM == 64 ? 2 : 4);
    __shared__ u16 As[2][BM * 64];
    __shared__ u16 Bs[2][BN * 64];
    int t = threadIdx.x;
    // XCD chunk swizzle over the (x,y) grid slice
    int nx = gridDim.x;
    int nwg = nx * gridDim.y;
    int bid = blockIdx.y * nx + blockIdx.x;
    int swz = (bid & 7) * (nwg >> 3) + (bid >> 3);
    int m0 = (swz / nx) * BM, n0 = (swz % nx) * BN;
    int w = t >> 6, lane = t & 63, quad = lane >> 4, l16 = lane & 15;
    int wm, wn;
    if (BM == 128 && BN == 128) { wm = (w >> 1) * 64; wn = (w & 1) * 64; }
    else if (BN == 64)          { wm = w * 32;        wn = 0; }
    else                        { wm = 0;             wn = w * 32; }

    f32x4 acc[MT][NT] = {};
    int sr = lane >> 3;                      // staging row within 8-row group
    int gc = ((lane & 7) ^ sr) * 8;          // swizzled source chunk (u16)
    int x7 = l16 & 7;                        // frag-read swizzle key
    const u16* gA = A + (size_t)m0 * lda;
    const u16* gB = Bt + (size_t)n0 * ldb;

    auto stage = [&](int k0, int buf) {
#pragma unroll
        for (int j = w; j < BM / 8; j += 4)
            gl_lds16(gA + (size_t)(j * 8 + sr) * lda + k0 + gc, &As[buf][j * 512]);
#pragma unroll
        for (int j = w; j < BN / 8; j += 4)
            gl_lds16(gB + (size_t)(j * 8 + sr) * ldb + k0 + gc, &Bs[buf][j * 512]);
    };

    stage(0, 0);
    int cur = 0;
    for (int k0 = 0; k0 < K; k0 += 64) {
        __syncthreads();   // drains DMA for cur (issued a full compute phase ago)
        if (k0 + 64 < K) stage(k0 + 64, cur ^ 1);   // DMA overlaps compute

#pragma unroll
        for (int s = 0; s < 2; s++) {
            bf16x8 af[MT], bfr[NT];
            int cp = ((s * 4 + quad) ^ x7) * 8;
#pragma unroll
            for (int mt = 0; mt < MT; mt++)
                af[mt] = *(const bf16x8*)&As[cur][(wm + mt * 16 + l16) * 64 + cp];
#pragma unroll
            for (int nt = 0; nt < NT; nt++)
                bfr[nt] = *(const bf16x8*)&Bs[cur][(wn + nt * 16 + l16) * 64 + cp];
#pragma unroll
            for (int mt = 0; mt < MT; mt++)
#pragma unroll
                for (int nt = 0; nt < NT; nt++)
                    acc[mt][nt] = __builtin_amdgcn_mfma_f32_16x16x32_bf16(af[mt], bfr[nt], acc[mt][nt], 0, 0, 0);
        }
        cur ^= 1;
    }

#pragma unroll
    for (int nt = 0; nt < NT; nt++) {
        int col = n0 + wn + nt * 16 + l16;
        float bc = (OUT_MODE == 3) ? 0.f : (BIAS_ROW ? 0.f : bias_at(bias, col));
#pragma unroll
        for (int mt = 0; mt < MT; mt++) {
#pragma unroll
            for (int r = 0; r < 4; r++) {
                int row = m0 + wm + mt * 16 + quad * 4 + r;
                float v = acc[mt][nt][r] + bc;
                if (OUT_MODE != 3 && BIAS_ROW) v += bias_at(bias, row);
                if (OUT_MODE == 1) v = fmaxf(v, 0.f);
                if (OUT_MODE == 2) {
                    v += res[(size_t)row * N + col];
                    ((float*)out)[(size_t)row * N + col] = v;
                } else if (OUT_MODE == 3) {
                    ((float*)out)[(size_t)row * N + col] = v;
                } else if (OUT_MODE == 4) {
                    int pc = (col & ~63) | (col & 32) | ((col & 0xC) << 1) |
                             ((col & 0x10) >> 2) | (col & 3);
                    ((u16*)out)[(size_t)row * N + pc] = f2bf(v);
                } else {
                    ((u16*)out)[(size_t)row * N + col] = f2bf(v);
                }
            }
        }
    }
}

template<int BM, int BN, int OUT_MODE, bool BIAS_ROW>
__global__ __launch_bounds__(256) void gemm128_kernel(const u16* __restrict__ A,
                                                      const u16* __restrict__ Bt,
                                                      Bias3 bias,
                                                      const float* res,
                                                      void* out,
                                                      int M, int N, int K) {
    gemm128_body<BM, BN, OUT_MODE, BIAS_ROW>(A, Bt, bias, res, out, M, N, K, K, K);
}

// split-K=2: z selects K-half; both halves write fp32 partials (reduced later).
// 128x128 tile, grid (8,32,2)=512 blocks -> 2/CU. Measured 47.4 us (round 5);
// the 8-phase 256x128 port regressed (50.0, round 6): NT=2 phases too fine.
__global__ __launch_bounds__(256) void gemm128_splitk2_kernel(const u16* __restrict__ A,
                                                              const u16* __restrict__ Bt,
                                                              float* __restrict__ p0,
                                                              float* __restrict__ p1,
                                                              int M, int N, int Kh, int ld) {
    int z = blockIdx.z;
    Bias3 dummy = { nullptr, nullptr, nullptr, 1 << 30, 1 << 30 };
    gemm128_body<128, 128, 3, false>(A + z * Kh, Bt + z * Kh, dummy, nullptr,
                                     z ? (void*)p1 : (void*)p0, M, N, Kh, ld, ld);
}

// d_out = p0 + p1 + bias[col] + res  (fp32)
__global__ __launch_bounds__(256) void ffn2_reduce_kernel(const float* __restrict__ p0,
                                                          const float* __restrict__ p1,
                                                          const float* __restrict__ b2,
                                                          const float* __restrict__ res,
                                                          float* __restrict__ out) {
    int i = (blockIdx.x * 256 + threadIdx.x) * 4;
    int col = i & (D_ - 1);
    float4 a = *(const float4*)(p0 + i);
    float4 b = *(const float4*)(p1 + i);
    float4 r = *(const float4*)(res + i);
    float4 bb = *(const float4*)(b2 + col);
    float4 o;
    o.x = a.x + b.x + r.x + bb.x;
    o.y = a.y + b.y + r.y + bb.y;
    o.z = a.z + b.z + r.z + bb.z;
    o.w = a.w + b.w + r.w + bb.w;
    *(float4*)(out + i) = o;
}

// two independent same-shape GEMMs in one launch (z selects).
// 128x128 tile (32 MFMA/K-step/wave), grid (8,32,2)=512 blocks -> 2/CU.
struct Pair2 {
    const u16* A0; const u16* A1;
    const u16* B0; const u16* B1;
    const float* b0; const float* b1;
    u16* o0; u16* o1;
};
__global__ __launch_bounds__(256) void gemm128_pairqk_kernel(Pair2 p, int M, int N, int K) {
    int z = blockIdx.z;
    const u16* A  = z ? p.A1 : p.A0;
    const u16* Bt = z ? p.B1 : p.B0;
    const float* bb = z ? p.b1 : p.b0;
    u16* o = z ? p.o1 : p.o0;
    Bias3 bs = { bb, bb, bb, 1 << 30, 1 << 30 };
    gemm128_body<128, 128, 0, false>(A, Bt, bs, nullptr, o, M, N, K, K, K);
}

// ---------------- 8-phase 256x256 GEMM (T3+T4+T5), bias+relu, bf16 out -----
// 512 threads = 8 waves (2M x 4N), per-wave 128x64 output, BK=64.
// LDS 128 KB flat: loop = As|Bs (2 bufs x 2 halves x [128][64] each, XOR-8
// chunk swizzle); epilogue REUSES it as the 256x256 bf16 output tile.
// Counted vmcnt(8) at tile boundaries (never 0 except last iter); raw s_barrier.
// Epilogue: acc -> LDS (quad-XOR slot swizzle) -> coalesced dwordx4 stores.
// Only used where grid >= 256 at 256^2 tile (FFN1) — smaller-N shapes regress.
__global__ __launch_bounds__(512) void gemm8p_kernel(const u16* __restrict__ A,
                                                     const u16* __restrict__ Bt,
                                                     const float* __restrict__ bias,
                                                     u16* __restrict__ out,
                                                     int M, int N, int K) {
    __shared__ u16 smem[65536];          // 128 KB
    u16* Asb = smem;                     // [(buf*2+half)*8192]
    u16* Bsb = smem + 32768;
    int t = threadIdx.x;
    int w = t >> 6, lane = t & 63, quad = lane >> 4, l16 = lane & 15;
    int wr = w >> 2, wc = w & 3;
    int nx = gridDim.x;
    int nwg = nx * gridDim.y;
    int bid = blockIdx.y * nx + blockIdx.x;
    int swz = (bid & 7) * (nwg >> 3) + (bid >> 3);
    int n0 = (swz % nx) * 256, m0 = (swz / nx) * 256;
    int sr = lane >> 3, gc = ((lane & 7) ^ sr) * 8;
    const u16* gA = A + (size_t)m0 * K;
    const u16* gB = Bt + (size_t)n0 * K;

    f32x4 acc[8][4] = {};
    int ntt = K >> 6;

    auto stageA = [&](int ti) {
        int buf = ti & 1, k0 = ti << 6;
        gl_lds16(gA + (size_t)(w * 8 + sr) * K + k0 + gc,             Asb + buf * 16384 + w * 512);
        gl_lds16(gA + (size_t)((w + 8) * 8 + sr) * K + k0 + gc,       Asb + buf * 16384 + (w + 8) * 512);
        gl_lds16(gA + (size_t)(128 + w * 8 + sr) * K + k0 + gc,       Asb + buf * 16384 + 8192 + w * 512);
        gl_lds16(gA + (size_t)(128 + (w + 8) * 8 + sr) * K + k0 + gc, Asb + buf * 16384 + 8192 + (w + 8) * 512);
    };
    auto stageB = [&](int ti) {
        int buf = ti & 1, k0 = ti << 6;
        gl_lds16(gB + (size_t)(w * 8 + sr) * K + k0 + gc,             Bsb + buf * 16384 + w * 512);
        gl_lds16(gB + (size_t)((w + 8) * 8 + sr) * K + k0 + gc,       Bsb + buf * 16384 + (w + 8) * 512);
        gl_lds16(gB + (size_t)(128 + w * 8 + sr) * K + k0 + gc,       Bsb + buf * 16384 + 8192 + w * 512);
        gl_lds16(gB + (size_t)(128 + (w + 8) * 8 + sr) * K + k0 + gc, Bsb + buf * 16384 + 8192 + (w + 8) * 512);
    };

    stageA(0); stageB(0);
    stageA(1); stageB(1);

    for (int ti = 0; ti < ntt; ++ti) {
        int buf = ti & 1;
        if (ti == ntt - 1) asm volatile("s_waitcnt vmcnt(0)" ::: "memory");
        else               asm volatile("s_waitcnt vmcnt(8)" ::: "memory");
        __builtin_amdgcn_sched_barrier(0);
        barrier_c();
        const u16* Ah = Asb + buf * 16384 + wr * 8192;
        const u16* Bh = Bsb + buf * 16384 + (wc >> 1) * 8192;
        int br0 = (wc & 1) * 64;
        bf16x8 a0[8], a1[8], b0[4], b1[4];

        // P0: read A kk0 (8) + B kk0 (4); MFMA mt0-3 x kk0
#pragma unroll
        for (int mt = 0; mt < 8; mt++) {
            int lr = mt * 16 + l16;
            a0[mt] = *(const bf16x8*)&Ah[lr * 64 + ((quad ^ (lr & 7)) * 8)];
        }
#pragma unroll
        for (int nt = 0; nt < 4; nt++) {
            int lr = br0 + nt * 16 + l16;
            b0[nt] = *(const bf16x8*)&Bh[lr * 64 + ((quad ^ (lr & 7)) * 8)];
        }
        __builtin_amdgcn_s_setprio(1);
#pragma unroll
        for (int mt = 0; mt < 4; mt++)
#pragma unroll
            for (int nt = 0; nt < 4; nt++)
                acc[mt][nt] = __builtin_amdgcn_mfma_f32_16x16x32_bf16(a0[mt], b0[nt], acc[mt][nt], 0, 0, 0);
        __builtin_amdgcn_s_setprio(0);
        barrier_c();

        // P1: read A kk1 (8); MFMA mt4-7 x kk0
#pragma unroll
        for (int mt = 0; mt < 8; mt++) {
            int lr = mt * 16 + l16;
            a1[mt] = *(const bf16x8*)&Ah[lr * 64 + (((4 + quad) ^ (lr & 7)) * 8)];
        }
        __builtin_amdgcn_s_setprio(1);
#pragma unroll
        for (int mt = 4; mt < 8; mt++)
#pragma unroll
            for (int nt = 0; nt < 4; nt++)
                acc[mt][nt] = __builtin_amdgcn_mfma_f32_16x16x32_bf16(a0[mt], b0[nt], acc[mt][nt], 0, 0, 0);
        __builtin_amdgcn_s_setprio(0);
        asm volatile("s_waitcnt lgkmcnt(0)" ::: "memory");   // all A-reads landed
        __builtin_amdgcn_sched_barrier(0);
        barrier_c();

        // P2: read B kk1 (4) + stage A(ti+2) into just-freed A slots; MFMA mt0-3 x kk1
#pragma unroll
        for (int nt = 0; nt < 4; nt++) {
            int lr = br0 + nt * 16 + l16;
            b1[nt] = *(const bf16x8*)&Bh[lr * 64 + (((4 + quad) ^ (lr & 7)) * 8)];
        }
        if (ti + 2 < ntt) stageA(ti + 2);
        __builtin_amdgcn_s_setprio(1);
#pragma unroll
        for (int mt = 0; mt < 4; mt++)
#pragma unroll
            for (int nt = 0; nt < 4; nt++)
                acc[mt][nt] = __builtin_amdgcn_mfma_f32_16x16x32_bf16(a1[mt], b1[nt], acc[mt][nt], 0, 0, 0);
        __builtin_amdgcn_s_setprio(0);
        asm volatile("s_waitcnt lgkmcnt(0)" ::: "memory");   // all B-reads landed
        __builtin_amdgcn_sched_barrier(0);
        barrier_c();

        // P3: stage B(ti+2); MFMA mt4-7 x kk1
        if (ti + 2 < ntt) stageB(ti + 2);
        __builtin_amdgcn_s_setprio(1);
#pragma unroll
        for (int mt = 4; mt < 8; mt++)
#pragma unroll
            for (int nt = 0; nt < 4; nt++)
                acc[mt][nt] = __builtin_amdgcn_mfma_f32_16x16x32_bf16(a1[mt], b1[nt], acc[mt][nt], 0, 0, 0);
        __builtin_amdgcn_s_setprio(0);
        // next iteration's vmcnt + barrier closes the tile
    }

    // ---- epilogue: bias+relu -> LDS (swizzled) -> coalesced global stores ----
    barrier_c();                       // all LDS reads done; repurpose smem
    u16* ot = smem;                    // logical [256][256] u16, col ^ (quad<<4)
#pragma unroll
    for (int nt = 0; nt < 4; nt++) {
        float bc = bias[n0 + wc * 64 + nt * 16 + l16];
        int csw = wc * 64 + ((nt ^ quad) * 16) + l16;   // swizzled slot
#pragma unroll
        for (int mt = 0; mt < 8; mt++) {
#pragma unroll
            for (int r = 0; r < 4; r++) {
                int row = wr * 128 + mt * 16 + quad * 4 + r;
                ot[row * 256 + csw] = f2bf(fmaxf(acc[mt][nt][r] + bc, 0.f));
            }
        }
    }
    barrier_c();                       // all writes visible
    int tr = t >> 5, tc = t & 31;
#pragma unroll
    for (int ps = 0; ps < 16; ps++) {
        int row = ps * 16 + tr;
        int qd = (row >> 2) & 3;
        int csw = (tc * 8) ^ (qd << 4);
        bf16x8 v = *(const bf16x8*)&ot[row * 256 + csw];
        *(bf16x8*)&out[(size_t)(m0 + row) * N + n0 + tc * 8] = v;
    }
}

// ---------------- Flash attention ----------------
// One q-tile per block, grid.x = 16 (1024 blocks -> 4 resident/CU at 32 KB LDS).
// qt STAGGER: qt = (x + h + 4b) & 15, bijective per (h,b). Without it, CU c
// receives 4 blocks that all share qt == c%16 -> causal self-attn loads CUs
// with [4..64] chunk-units; staggered: [28..40]. No-op for cross-attn.
// Per-64-key double-buffered staging. S^T = K·Q^T via MFMA (operand swap) ->
// exp outputs land directly in the PV A-fragment (k-slot relabeling). V^T is
// stored with sigma-permuted keys (by the V-GEMM epilogue) so the PV B-fragment
// is ONE conflict-free XOR-8 ds_read_b128.
// Row-sum via MFMA with ones. No running max: scores bounded; clamp 20.
// __expf (NOT libm exp2f -- measured regression r7: precise-path guards).
__global__ __launch_bounds__(256) void attn_kernel(const u16* __restrict__ Q, int ldq,
                                                   const u16* __restrict__ Kb, int ldk,
                                                   const u16* __restrict__ Vt,
                                                   const int* __restrict__ mask,
                                                   const unsigned char* __restrict__ bmask,
                                                   u16* __restrict__ ctx) {
    __shared__ u16 Ks[2][64 * 64];   // [buf][key][dh], XOR-8 swizzled
    __shared__ u16 Vs[2][64 * 64];   // [buf][dh][perm-key], XOR-8 swizzled
    int t = threadIdx.x;
    int b = blockIdx.z, hh = blockIdx.y;
    int qt = ((int)blockIdx.x + hh + 4 * b) & 15;   // staggered q-tile
    int w = t >> 6, lane = t & 63, quad = lane >> 4, l16 = lane & 15;
    int hoff = hh * DH_;

    bf16x8 ones8;
#pragma unroll
    for (int j = 0; j < 8; j++) ones8[j] = (short)0x3F80;  // bf16 1.0

    // Q fragments (B-operand for S^T), scaled 1/8
    bf16x8 qf[2];
    int qrow = qt * 64 + w * 16 + l16;
#pragma unroll
    for (int kk = 0; kk < 2; kk++) {
        bf16x8 v = *(const bf16x8*)(Q + (size_t)(b * S_ + qrow) * ldq + hoff + kk * 32 + quad * 8);
#pragma unroll
        for (int j = 0; j < 8; j++)
            v[j] = (short)f2bf(bf2f((u16)v[j]) * 0.125f);
        qf[kk] = v;
    }

    f32x4 oacc[4] = {};
    f32x4 lacc = {};

    // block-mask bitfields over 16 64-key chunks (wave-uniform)
    unsigned nz = 0, mx = 0;
    for (int c = 0; c < 16; c++) {
        int v = bmask ? (int)bmask[(b * 16 + qt) * 16 + c] : 1;
        if (v)      nz |= 1u << c;
        if (v == 1) mx |= 1u << c;
    }

    int sr = lane >> 3;                  // staging row within 8-row group
    int gc = ((lane & 7) ^ sr) * 8;      // swizzled source chunk (u16)

    auto stage64 = [&](int c, int buf) {
        int k0 = c * 64;
        for (int j = w; j < 8; j += 4) {
            gl_lds16(Kb + (size_t)(b * S_ + k0 + j * 8 + sr) * ldk + hoff + gc, &Ks[buf][j * 512]);
            gl_lds16(Vt + (size_t)(hoff + j * 8 + sr) * (B_ * S_) + b * S_ + k0 + gc, &Vs[buf][j * 512]);
        }
    };

    unsigned rem = nz;
    int c = rem ? __builtin_ctz(rem) : -1;
    if (c >= 0) stage64(c, 0);
    int cur = 0;

    while (c >= 0) {
        rem &= rem - 1;
        int nc = rem ? __builtin_ctz(rem) : -1;
        __syncthreads();                     // drain staging of cur; readers of cur^1 done
        if (nc >= 0) stage64(nc, cur ^ 1);   // DMA overlaps compute below

        int k0c = c * 64;
        bool mixed = (mx >> c) & 1u;
        const u16* KsT = Ks[cur];
        const u16* VsT = Vs[cur];

        // S^T tile: lane holds S[q = qrow][key = k0c+nt*16+quad*4+r]
        float p[4][4];
#pragma unroll
        for (int nt = 0; nt < 4; nt++) {
            f32x4 sacc = {};
            int krow = nt * 16 + l16;
            __builtin_amdgcn_s_setprio(1);
#pragma unroll
            for (int kk = 0; kk < 2; kk++) {
                int cp = ((kk * 4 + quad) ^ (krow & 7)) * 8;
                bf16x8 kf = *(const bf16x8*)&KsT[krow * 64 + cp];
                sacc = __builtin_amdgcn_mfma_f32_16x16x32_bf16(kf, qf[kk], sacc, 0, 0, 0);
            }
            __builtin_amdgcn_s_setprio(0);
#pragma unroll
            for (int r = 0; r < 4; r++) {
                float sv = sacc[r];
                if (mixed) {
                    int kc = k0c + nt * 16 + quad * 4 + r;
                    if (mask[(size_t)(b * S_ + qrow) * S_ + kc] == 0) sv = -1e9f;
                }
                p[nt][r] = __expf(fminf(sv, 20.f));
            }
        }

        // PV + rowsum directly from registers (k-slot relabeled x32 MFMA).
        // V-fragment: single b128 read thanks to sigma-permuted Vs layout.
#pragma unroll
        for (int mp = 0; mp < 2; mp++) {
            bf16x8 af;
#pragma unroll
            for (int r = 0; r < 4; r++) {
                af[r]     = (short)f2bf(p[2 * mp][r]);
                af[4 + r] = (short)f2bf(p[2 * mp + 1][r]);
            }
            __builtin_amdgcn_s_setprio(1);
            lacc = __builtin_amdgcn_mfma_f32_16x16x32_bf16(af, ones8, lacc, 0, 0, 0);
#pragma unroll
            for (int dt = 0; dt < 4; dt++) {
                int vrow = dt * 16 + l16;
                int ch = (mp * 4 + quad) ^ (vrow & 7);
                bf16x8 vf = *(const bf16x8*)&VsT[vrow * 64 + ch * 8];
                oacc[dt] = __builtin_amdgcn_mfma_f32_16x16x32_bf16(af, vf, oacc[dt], 0, 0, 0);
            }
            __builtin_amdgcn_s_setprio(0);
        }
        c = nc;
        cur ^= 1;
    }

#pragma unroll
    for (int dt = 0; dt < 4; dt++)
#pragma unroll
        for (int r = 0; r < 4; r++) {
            int qq = qt * 64 + w * 16 + quad * 4 + r;
            float l = lacc[r];
            float inv = l > 0.f ? 1.f / l : 0.f;
            ctx[(size_t)(b * S_ + qq) * D_ + hoff + dt * 16 + l16] = f2bf(oacc[dt][r] * inv);
        }
}

extern "C" void kernel_launch(void* const* d_in, const int* in_sizes, int n_in,
                              void* d_out, int out_size, void* d_ws, size_t ws_size,
                              hipStream_t stream) {
    const float* x     = (const float*)d_in[0];
    const float* srcx  = (const float*)d_in[1];
    const int*   mask  = (const int*)d_in[2];
    const int*   smask = (const int*)d_in[3];
    const float* ln1g = (const float*)d_in[4],  *ln1b = (const float*)d_in[5];
    const float* ln2g = (const float*)d_in[6],  *ln2b = (const float*)d_in[7];
    const float* ln3g = (const float*)d_in[8],  *ln3b = (const float*)d_in[9];
    const float* sa_wq = (const float*)d_in[10], *sa_bq = (const float*)d_in[11];
    const float* sa_wk = (const float*)d_in[12], *sa_bk = (const float*)d_in[13];
    const float* sa_wv = (const float*)d_in[14], *sa_bv = (const float*)d_in[15];
    const float* sa_wo = (const float*)d_in[16], *sa_bo = (const float*)d_in[17];
    const float* ca_wq = (const float*)d_in[18], *ca_bq = (const float*)d_in[19];
    const float* ca_wk = (const float*)d_in[20], *ca_bk = (const float*)d_in[21];
    const float* ca_wv = (const float*)d_in[22], *ca_bv = (const float*)d_in[23];
    const float* ca_wo = (const float*)d_in[24], *ca_bo = (const float*)d_in[25];
    const float* ff_w1 = (const float*)d_in[26], *ff_b1 = (const float*)d_in[27];
    const float* ff_w2 = (const float*)d_in[28], *ff_b2 = (const float*)d_in[29];

    char* ws = (char*)d_ws;
    const size_t MB = 1ull << 20;
    const size_t DD = (size_t)D_ * D_;
    float* xcur = (float*)ws;                  // 16 MB fp32 residual
    u16* h     = (u16*)(ws + 16 * MB);         // 8 MB LN output
    u16* qk    = (u16*)(ws + 24 * MB);         // self: [4096][2048] 16 MB
    u16* qb    = (u16*)(ws + 24 * MB);         // cross Q [4096][1024] 8 MB
    u16* kbuf  = (u16*)(ws + 32 * MB);         // cross K 8 MB
    u16* vt    = (u16*)(ws + 40 * MB);         // V^T [1024][4096] 8 MB (perm keys)
    u16* ctx   = (u16*)(ws + 48 * MB);         // 8 MB
    u16* ff    = (u16*)(ws + 24 * MB);         // ffn [4096][4096] 32 MB (reuse)
    u16* sxb   = (u16*)(ws + 56 * MB);         // bf16 src_x 8 MB
    u16* wqk_s = (u16*)(ws + 64 * MB);         // [2048][1024] 4 MB
    u16* wv_s  = (u16*)(ws + 68 * MB);
    u16* wo_s  = (u16*)(ws + 70 * MB);
    u16* wq_c  = (u16*)(ws + 72 * MB);
    u16* wk_c  = (u16*)(ws + 74 * MB);
    u16* wv_c  = (u16*)(ws + 76 * MB);
    u16* wo_c  = (u16*)(ws + 78 * MB);
    u16* wff1  = (u16*)(ws + 80 * MB);         // [4096][1024] 8 MB
    u16* wff2  = (u16*)(ws + 88 * MB);         // [1024][4096] 8 MB
    // FFN2 split-K partials: these regions are dead by FFN time
    // (sxb + staged self/cross weights + wff1 all consumed).
    float* fp0 = (float*)(ws + 56 * MB);       // 16 MB fp32 partial (k 0..2047)
    float* fp1 = (float*)(ws + 72 * MB);       // 16 MB fp32 partial (k 2048..4095)
    unsigned char* bm_self = nullptr, *bm_cross = nullptr;
    if (ws_size >= 96 * MB + 8192) {           // constant across calls -> graph-safe
        bm_self  = (unsigned char*)(ws + ws_size - 8192);
        bm_cross = bm_self + 4096;
    }

    dim3 blk(256);

    // ---- setup: weight transposes, src_x convert, mask classify ----
    TP tp = {{sa_wq, sa_wk, sa_wv, sa_wo, ca_wq, ca_wk, ca_wv, ca_wo},
             {wqk_s, wqk_s + DD, wv_s, wo_s, wq_c, wk_c, wv_c, wo_c}};
    trcvt8_kernel<<<dim3(16, 16, 8), blk, 0, stream>>>(tp);
    trcvt_kernel<<<dim3(F_ / 64, D_ / 64), blk, 0, stream>>>(ff_w1, wff1, D_, F_);
    trcvt_kernel<<<dim3(D_ / 64, F_ / 64), blk, 0, stream>>>(ff_w2, wff2, F_, D_);
    cvt1_kernel<<<B_ * S_ * D_ / 1024, blk, 0, stream>>>(srcx, sxb);
    if (bm_self) {
        mask_reduce_kernel<<<dim3(256, B_), blk, 0, stream>>>(mask, bm_self);
        mask_reduce_kernel<<<dim3(256, B_), blk, 0, stream>>>(smask, bm_cross);
    }

    Bias3 bqk = { sa_bq, sa_bk, sa_bk, 1024, 2048 };
    Bias3 bsv = { sa_bv, sa_bv, sa_bv, 1 << 30, 1 << 30 };
    Bias3 bso = { sa_bo, sa_bo, sa_bo, 1 << 30, 1 << 30 };
    Bias3 bcv = { ca_bv, ca_bv, ca_bv, 1 << 30, 1 << 30 };
    Bias3 bco = { ca_bo, ca_bo, ca_bo, 1 << 30, 1 << 30 };

    // ---- self attention ----
    ln_kernel<true><<<B_ * S_, blk, 0, stream>>>(x, ln1g, ln1b, xcur, h);
    gemm128_kernel<128,128,0,false><<<dim3(16, 32), blk, 0, stream>>>(h, wqk_s, bqk, nullptr, qk, 4096, 2048, 1024);
    gemm128_kernel<64,128,4,true><<<dim3(32, 16), blk, 0, stream>>>(wv_s, h, bsv, nullptr, vt, 1024, 4096, 1024);
    attn_kernel<<<dim3(16, H_, B_), blk, 0, stream>>>(qk, 2048, qk + 1024, 2048, vt, mask, bm_self, ctx);
    gemm128_kernel<128,64,2,false><<<dim3(16, 32), blk, 0, stream>>>(ctx, wo_s, bso, xcur, xcur, 4096, 1024, 1024);

    // ---- cross attention ----
    ln_kernel<false><<<B_ * S_, blk, 0, stream>>>(xcur, ln2g, ln2b, nullptr, h);
    {
        Pair2 pqk = { h, sxb, wq_c, wk_c, ca_bq, ca_bk, qb, kbuf };
        gemm128_pairqk_kernel<<<dim3(8, 32, 2), blk, 0, stream>>>(pqk, 4096, 1024, 1024);
    }
    gemm128_kernel<64,128,4,true><<<dim3(32, 16), blk, 0, stream>>>(wv_c, sxb, bcv, nullptr, vt, 1024, 4096, 1024);
    attn_kernel<<<dim3(16, H_, B_), blk, 0, stream>>>(qb, 1024, kbuf, 1024, vt, smask, bm_cross, ctx);
    gemm128_kernel<128,64,2,false><<<dim3(16, 32), blk, 0, stream>>>(ctx, wo_c, bco, xcur, xcur, 4096, 1024, 1024);

    // ---- FFN ----
    ln_kernel<false><<<B_ * S_, blk, 0, stream>>>(xcur, ln3g, ln3b, nullptr, h);
    gemm8p_kernel<<<dim3(16, 16), dim3(512), 0, stream>>>(h, wff1, ff_b1, ff, 4096, 4096, 1024);
    gemm128_splitk2_kernel<<<dim3(8, 32, 2), blk, 0, stream>>>(ff, wff2, fp0, fp1, 4096, 1024, 2048, 4096);
    ffn2_reduce_kernel<<<dim3(B_ * S_ * D_ / 1024), blk, 0, stream>>>(fp0, fp1, ff_b2, xcur, (float*)d_out);
}

// Round 10
// 520.680 us; speedup vs baseline: 1.0350x; 1.0184x over previous
//
#include <hip/hip_runtime.h>
#include <hip/hip_bf16.h>

#define B_ 4
#define S_ 1024
#define D_ 1024
#define H_ 16
#define DH_ 64
#define F_ 4096

typedef unsigned short u16;
typedef unsigned int u32;
typedef __attribute__((ext_vector_type(8))) short bf16x8;
typedef __attribute__((ext_vector_type(4))) short bf16x4;
typedef __attribute__((ext_vector_type(4))) float f32x4;

__device__ __forceinline__ float bf2f(u16 u) {
    return __uint_as_float(((u32)u) << 16);
}
__device__ __forceinline__ u16 f2bf(float f) {
    __hip_bfloat16 h = __float2bfloat16(f);
    return *reinterpret_cast<u16*>(&h);
}

typedef __attribute__((address_space(1))) const u32 gu32;
typedef __attribute__((address_space(3))) u32 lu32;
__device__ __forceinline__ void gl_lds16(const void* g, void* l) {
    // async global->LDS, 16B/lane, dest = wave-uniform base + lane*16
    __builtin_amdgcn_global_load_lds((gu32*)g, (lu32*)l, 16, 0, 0);
}

__device__ __forceinline__ void barrier_c() {
    asm volatile("" ::: "memory");
    __builtin_amdgcn_s_barrier();
    asm volatile("" ::: "memory");
}

// ---------------- fp32->bf16 elementwise ----------------
__global__ __launch_bounds__(256) void cvt1_kernel(const float* __restrict__ s,
                                                   u16* __restrict__ d) {
    int i = (blockIdx.x * 256 + threadIdx.x) * 4;
    float4 v = *(const float4*)(s + i);
    u16 o0 = f2bf(v.x), o1 = f2bf(v.y), o2 = f2bf(v.z), o3 = f2bf(v.w);
    d[i] = o0; d[i+1] = o1; d[i+2] = o2; d[i+3] = o3;
}

// ---------------- transpose + convert: src fp32 [K][N] -> dst bf16 [N][K] ----
__device__ __forceinline__ void trcvt_body(const float* __restrict__ src,
                                           u16* __restrict__ dst, int K, int N,
                                           int n0, int k0) {
    __shared__ u16 tile[64][65];
    int t = threadIdx.x;
    int c = t & 63, r4 = t >> 6;
#pragma unroll
    for (int i = 0; i < 16; i++) {
        int r = i * 4 + r4;
        tile[c][r] = f2bf(src[(size_t)(k0 + r) * N + n0 + c]);
    }
    __syncthreads();
#pragma unroll
    for (int i = 0; i < 16; i++) {
        int rr = i * 4 + r4;
        dst[(size_t)(n0 + rr) * K + k0 + c] = tile[rr][c];
    }
}

__global__ __launch_bounds__(256) void trcvt_kernel(const float* __restrict__ src,
                                                    u16* __restrict__ dst,
                                                    int K, int N) {
    trcvt_body(src, dst, K, N, blockIdx.x * 64, blockIdx.y * 64);
}

struct TP { const float* src[8]; u16* dst[8]; };
__global__ __launch_bounds__(256) void trcvt8_kernel(TP tp) {
    trcvt_body(tp.src[blockIdx.z], tp.dst[blockIdx.z], D_, D_,
               blockIdx.x * 64, blockIdx.y * 64);
}

// ---------------- mask block classify: 0=all-drop, 1=mixed, 2=all-keep ------
__global__ __launch_bounds__(256) void mask_reduce_kernel(const int* __restrict__ mask,
                                                          unsigned char* __restrict__ bmask) {
    int t = threadIdx.x;
    int qb = blockIdx.x >> 4, kb = blockIdx.x & 15, b = blockIdx.y;
    bool all1 = true, any1 = false;
#pragma unroll
    for (int i = 0; i < 16; i++) {
        int e = t + i * 256;
        int r = e >> 6, c = e & 63;
        int v = mask[((size_t)(b * S_ + qb * 64 + r)) * S_ + kb * 64 + c];
        all1 = all1 && (v != 0);
        any1 = any1 || (v != 0);
    }
    unsigned long long ba = __ballot(all1), bn = __ballot(any1);
    __shared__ unsigned long long sa[4], sn[4];
    if ((t & 63) == 0) { sa[t >> 6] = ba; sn[t >> 6] = bn; }
    __syncthreads();
    if (t == 0) {
        bool A = ((sa[0] & sa[1] & sa[2] & sa[3]) == ~0ull);
        bool Y = ((sn[0] | sn[1] | sn[2] | sn[3]) != 0ull);
        bmask[b * 256 + blockIdx.x] = A ? 2 : (Y ? 1 : 0);
    }
}

// ---------------- LayerNorm ----------------
template<bool COPY>
__global__ __launch_bounds__(256) void ln_kernel(const float* __restrict__ xin,
                                                 const float* __restrict__ g,
                                                 const float* __restrict__ bta,
                                                 float* xcur,
                                                 u16* __restrict__ hout) {
    int row = blockIdx.x;
    int t = threadIdx.x;
    size_t base = (size_t)row * D_;
    float v[4];
#pragma unroll
    for (int i = 0; i < 4; i++) v[i] = xin[base + t + i * 256];
    float s  = v[0] + v[1] + v[2] + v[3];
    float s2 = v[0]*v[0] + v[1]*v[1] + v[2]*v[2] + v[3]*v[3];
#pragma unroll
    for (int m = 1; m < 64; m <<= 1) {
        s  += __shfl_xor(s, m);
        s2 += __shfl_xor(s2, m);
    }
    __shared__ float red[8];
    int wave = t >> 6;
    if ((t & 63) == 0) { red[wave*2] = s; red[wave*2+1] = s2; }
    __syncthreads();
    float fs  = red[0] + red[2] + red[4] + red[6];
    float fs2 = red[1] + red[3] + red[5] + red[7];
    float mu  = fs * (1.0f / D_);
    float var = fs2 * (1.0f / D_) - mu * mu;
    float rs  = rsqrtf(var + 1e-5f);
#pragma unroll
    for (int i = 0; i < 4; i++) {
        int c = t + i * 256;
        float x = v[i];
        if (COPY) xcur[base + c] = x;
        hout[base + c] = f2bf((x - mu) * rs * g[c] + bta[c]);
    }
}

// ---------------- GEMM: C[M,N] = act(A[M,K] @ Bt[N,K]^T + bias [+ res]) -----
// BK=64, XOR-8 chunk swizzle, single-barrier double-buffered K-loop.
// XCD-aware chunked block swizzle (T1): bijective since all grids %8 == 0.
struct Bias3 { const float* b0; const float* b1; const float* b2; int n1; int n2; };

__device__ __forceinline__ float bias_at(const Bias3& bs, int c) {
    const float* p; int o;
    if (c < bs.n1)      { p = bs.b0; o = c; }
    else if (c < bs.n2) { p = bs.b1; o = c - bs.n1; }
    else                { p = bs.b2; o = c - bs.n2; }
    return p[o];
}

// OUT_MODE: 0 = bf16 out; 1 = bf16 out + relu; 2 = fp32 out + fp32 residual;
//           3 = fp32 raw partial (no bias, no res) -- for split-K;
//           4 = bf16 out with key-permuted column within each 64-block
//               (sigma: 32m+16h+4q+r -> 32m+8q+4h+r) for attn PV b128 reads.
// BIAS_ROW: bias indexed by output row (m) instead of col (n).
template<int BM, int BN, int OUT_MODE, bool BIAS_ROW>
__device__ __forceinline__ void gemm128_body(const u16* __restrict__ A,
                                             const u16* __restrict__ Bt,
                                             Bias3 bias,
                                             const float* res,
                                             void* out,
                                             int M, int N, int K,
                                             int lda, int ldb) {
    constexpr int MT = (BM == 64) ? 4 : (BN == 64 ? 2 : 4);
    constexpr int NT = (BN == 64) ? 4 : (BM == 64 ? 2 : 4);
    __shared__ u16 As[2][BM * 64];
    __shared__ u16 Bs[2][BN * 64];
    int t = threadIdx.x;
    // XCD chunk swizzle over the (x,y) grid slice
    int nx = gridDim.x;
    int nwg = nx * gridDim.y;
    int bid = blockIdx.y * nx + blockIdx.x;
    int swz = (bid & 7) * (nwg >> 3) + (bid >> 3);
    int m0 = (swz / nx) * BM, n0 = (swz % nx) * BN;
    int w = t >> 6, lane = t & 63, quad = lane >> 4, l16 = lane & 15;
    int wm, wn;
    if (BM == 128 && BN == 128) { wm = (w >> 1) * 64; wn = (w & 1) * 64; }
    else if (BN == 64)          { wm = w * 32;        wn = 0; }
    else                        { wm = 0;             wn = w * 32; }

    f32x4 acc[MT][NT] = {};
    int sr = lane >> 3;                      // staging row within 8-row group
    int gc = ((lane & 7) ^ sr) * 8;          // swizzled source chunk (u16)
    int x7 = l16 & 7;                        // frag-read swizzle key
    const u16* gA = A + (size_t)m0 * lda;
    const u16* gB = Bt + (size_t)n0 * ldb;

    auto stage = [&](int k0, int buf) {
#pragma unroll
        for (int j = w; j < BM / 8; j += 4)
            gl_lds16(gA + (size_t)(j * 8 + sr) * lda + k0 + gc, &As[buf][j * 512]);
#pragma unroll
        for (int j = w; j < BN / 8; j += 4)
            gl_lds16(gB + (size_t)(j * 8 + sr) * ldb + k0 + gc, &Bs[buf][j * 512]);
    };

    stage(0, 0);
    int cur = 0;
    for (int k0 = 0; k0 < K; k0 += 64) {
        __syncthreads();   // drains DMA for cur (issued a full compute phase ago)
        if (k0 + 64 < K) stage(k0 + 64, cur ^ 1);   // DMA overlaps compute

#pragma unroll
        for (int s = 0; s < 2; s++) {
            bf16x8 af[MT], bfr[NT];
            int cp = ((s * 4 + quad) ^ x7) * 8;
#pragma unroll
            for (int mt = 0; mt < MT; mt++)
                af[mt] = *(const bf16x8*)&As[cur][(wm + mt * 16 + l16) * 64 + cp];
#pragma unroll
            for (int nt = 0; nt < NT; nt++)
                bfr[nt] = *(const bf16x8*)&Bs[cur][(wn + nt * 16 + l16) * 64 + cp];
#pragma unroll
            for (int mt = 0; mt < MT; mt++)
#pragma unroll
                for (int nt = 0; nt < NT; nt++)
                    acc[mt][nt] = __builtin_amdgcn_mfma_f32_16x16x32_bf16(af[mt], bfr[nt], acc[mt][nt], 0, 0, 0);
        }
        cur ^= 1;
    }

#pragma unroll
    for (int nt = 0; nt < NT; nt++) {
        int col = n0 + wn + nt * 16 + l16;
        float bc = (OUT_MODE == 3) ? 0.f : (BIAS_ROW ? 0.f : bias_at(bias, col));
#pragma unroll
        for (int mt = 0; mt < MT; mt++) {
#pragma unroll
            for (int r = 0; r < 4; r++) {
                int row = m0 + wm + mt * 16 + quad * 4 + r;
                float v = acc[mt][nt][r] + bc;
                if (OUT_MODE != 3 && BIAS_ROW) v += bias_at(bias, row);
                if (OUT_MODE == 1) v = fmaxf(v, 0.f);
                if (OUT_MODE == 2) {
                    v += res[(size_t)row * N + col];
                    ((float*)out)[(size_t)row * N + col] = v;
                } else if (OUT_MODE == 3) {
                    ((float*)out)[(size_t)row * N + col] = v;
                } else if (OUT_MODE == 4) {
                    int pc = (col & ~63) | (col & 32) | ((col & 0xC) << 1) |
                             ((col & 0x10) >> 2) | (col & 3);
                    ((u16*)out)[(size_t)row * N + pc] = f2bf(v);
                } else {
                    ((u16*)out)[(size_t)row * N + col] = f2bf(v);
                }
            }
        }
    }
}

template<int BM, int BN, int OUT_MODE, bool BIAS_ROW>
__global__ __launch_bounds__(256) void gemm128_kernel(const u16* __restrict__ A,
                                                      const u16* __restrict__ Bt,
                                                      Bias3 bias,
                                                      const float* res,
                                                      void* out,
                                                      int M, int N, int K) {
    gemm128_body<BM, BN, OUT_MODE, BIAS_ROW>(A, Bt, bias, res, out, M, N, K, K, K);
}

// split-K=2: z selects K-half; both halves write fp32 partials (reduced later).
// 128x128 tile, grid (8,32,2)=512 blocks -> 2/CU. Measured 45.6-47.4 us =
// the 128^2-structure ceiling for this shape (8-phase port regressed, r6).
__global__ __launch_bounds__(256) void gemm128_splitk2_kernel(const u16* __restrict__ A,
                                                              const u16* __restrict__ Bt,
                                                              float* __restrict__ p0,
                                                              float* __restrict__ p1,
                                                              int M, int N, int Kh, int ld) {
    int z = blockIdx.z;
    Bias3 dummy = { nullptr, nullptr, nullptr, 1 << 30, 1 << 30 };
    gemm128_body<128, 128, 3, false>(A + z * Kh, Bt + z * Kh, dummy, nullptr,
                                     z ? (void*)p1 : (void*)p0, M, N, Kh, ld, ld);
}

// d_out = p0 + p1 + bias[col] + res  (fp32)
__global__ __launch_bounds__(256) void ffn2_reduce_kernel(const float* __restrict__ p0,
                                                          const float* __restrict__ p1,
                                                          const float* __restrict__ b2,
                                                          const float* __restrict__ res,
                                                          float* __restrict__ out) {
    int i = (blockIdx.x * 256 + threadIdx.x) * 4;
    int col = i & (D_ - 1);
    float4 a = *(const float4*)(p0 + i);
    float4 b = *(const float4*)(p1 + i);
    float4 r = *(const float4*)(res + i);
    float4 bb = *(const float4*)(b2 + col);
    float4 o;
    o.x = a.x + b.x + r.x + bb.x;
    o.y = a.y + b.y + r.y + bb.y;
    o.z = a.z + b.z + r.z + bb.z;
    o.w = a.w + b.w + r.w + bb.w;
    *(float4*)(out + i) = o;
}

// two independent same-shape GEMMs in one launch (z selects).
// 128x128 tile (32 MFMA/K-step/wave), grid (8,32,2)=512 blocks -> 2/CU.
struct Pair2 {
    const u16* A0; const u16* A1;
    const u16* B0; const u16* B1;
    const float* b0; const float* b1;
    u16* o0; u16* o1;
};
__global__ __launch_bounds__(256) void gemm128_pairqk_kernel(Pair2 p, int M, int N, int K) {
    int z = blockIdx.z;
    const u16* A  = z ? p.A1 : p.A0;
    const u16* Bt = z ? p.B1 : p.B0;
    const float* bb = z ? p.b1 : p.b0;
    u16* o = z ? p.o1 : p.o0;
    Bias3 bs = { bb, bb, bb, 1 << 30, 1 << 30 };
    gemm128_body<128, 128, 0, false>(A, Bt, bs, nullptr, o, M, N, K, K, K);
}

// ---------------- 8-phase 256x256 GEMM (T3+T4+T5), bias+relu, bf16 out -----
// 512 threads = 8 waves (2M x 4N), per-wave 128x64 output, BK=64.
// LDS 128 KB flat: loop = As|Bs (2 bufs x 2 halves x [128][64] each, XOR-8
// chunk swizzle); epilogue REUSES it as the 256x256 bf16 output tile.
// Counted vmcnt(8) at tile boundaries (never 0 except last iter); raw s_barrier.
// Epilogue: acc -> LDS (quad-XOR slot swizzle) -> coalesced dwordx4 stores.
// Only used where grid >= 256 at 256^2 tile (FFN1) — smaller-N shapes regress.
__global__ __launch_bounds__(512) void gemm8p_kernel(const u16* __restrict__ A,
                                                     const u16* __restrict__ Bt,
                                                     const float* __restrict__ bias,
                                                     u16* __restrict__ out,
                                                     int M, int N, int K) {
    __shared__ u16 smem[65536];          // 128 KB
    u16* Asb = smem;                     // [(buf*2+half)*8192]
    u16* Bsb = smem + 32768;
    int t = threadIdx.x;
    int w = t >> 6, lane = t & 63, quad = lane >> 4, l16 = lane & 15;
    int wr = w >> 2, wc = w & 3;
    int nx = gridDim.x;
    int nwg = nx * gridDim.y;
    int bid = blockIdx.y * nx + blockIdx.x;
    int swz = (bid & 7) * (nwg >> 3) + (bid >> 3);
    int n0 = (swz % nx) * 256, m0 = (swz / nx) * 256;
    int sr = lane >> 3, gc = ((lane & 7) ^ sr) * 8;
    const u16* gA = A + (size_t)m0 * K;
    const u16* gB = Bt + (size_t)n0 * K;

    f32x4 acc[8][4] = {};
    int ntt = K >> 6;

    auto stageA = [&](int ti) {
        int buf = ti & 1, k0 = ti << 6;
        gl_lds16(gA + (size_t)(w * 8 + sr) * K + k0 + gc,             Asb + buf * 16384 + w * 512);
        gl_lds16(gA + (size_t)((w + 8) * 8 + sr) * K + k0 + gc,       Asb + buf * 16384 + (w + 8) * 512);
        gl_lds16(gA + (size_t)(128 + w * 8 + sr) * K + k0 + gc,       Asb + buf * 16384 + 8192 + w * 512);
        gl_lds16(gA + (size_t)(128 + (w + 8) * 8 + sr) * K + k0 + gc, Asb + buf * 16384 + 8192 + (w + 8) * 512);
    };
    auto stageB = [&](int ti) {
        int buf = ti & 1, k0 = ti << 6;
        gl_lds16(gB + (size_t)(w * 8 + sr) * K + k0 + gc,             Bsb + buf * 16384 + w * 512);
        gl_lds16(gB + (size_t)((w + 8) * 8 + sr) * K + k0 + gc,       Bsb + buf * 16384 + (w + 8) * 512);
        gl_lds16(gB + (size_t)(128 + w * 8 + sr) * K + k0 + gc,       Bsb + buf * 16384 + 8192 + w * 512);
        gl_lds16(gB + (size_t)(128 + (w + 8) * 8 + sr) * K + k0 + gc, Bsb + buf * 16384 + 8192 + (w + 8) * 512);
    };

    stageA(0); stageB(0);
    stageA(1); stageB(1);

    for (int ti = 0; ti < ntt; ++ti) {
        int buf = ti & 1;
        if (ti == ntt - 1) asm volatile("s_waitcnt vmcnt(0)" ::: "memory");
        else               asm volatile("s_waitcnt vmcnt(8)" ::: "memory");
        __builtin_amdgcn_sched_barrier(0);
        barrier_c();
        const u16* Ah = Asb + buf * 16384 + wr * 8192;
        const u16* Bh = Bsb + buf * 16384 + (wc >> 1) * 8192;
        int br0 = (wc & 1) * 64;
        bf16x8 a0[8], a1[8], b0[4], b1[4];

        // P0: read A kk0 (8) + B kk0 (4); MFMA mt0-3 x kk0
#pragma unroll
        for (int mt = 0; mt < 8; mt++) {
            int lr = mt * 16 + l16;
            a0[mt] = *(const bf16x8*)&Ah[lr * 64 + ((quad ^ (lr & 7)) * 8)];
        }
#pragma unroll
        for (int nt = 0; nt < 4; nt++) {
            int lr = br0 + nt * 16 + l16;
            b0[nt] = *(const bf16x8*)&Bh[lr * 64 + ((quad ^ (lr & 7)) * 8)];
        }
        __builtin_amdgcn_s_setprio(1);
#pragma unroll
        for (int mt = 0; mt < 4; mt++)
#pragma unroll
            for (int nt = 0; nt < 4; nt++)
                acc[mt][nt] = __builtin_amdgcn_mfma_f32_16x16x32_bf16(a0[mt], b0[nt], acc[mt][nt], 0, 0, 0);
        __builtin_amdgcn_s_setprio(0);
        barrier_c();

        // P1: read A kk1 (8); MFMA mt4-7 x kk0
#pragma unroll
        for (int mt = 0; mt < 8; mt++) {
            int lr = mt * 16 + l16;
            a1[mt] = *(const bf16x8*)&Ah[lr * 64 + (((4 + quad) ^ (lr & 7)) * 8)];
        }
        __builtin_amdgcn_s_setprio(1);
#pragma unroll
        for (int mt = 4; mt < 8; mt++)
#pragma unroll
            for (int nt = 0; nt < 4; nt++)
                acc[mt][nt] = __builtin_amdgcn_mfma_f32_16x16x32_bf16(a0[mt], b0[nt], acc[mt][nt], 0, 0, 0);
        __builtin_amdgcn_s_setprio(0);
        asm volatile("s_waitcnt lgkmcnt(0)" ::: "memory");   // all A-reads landed
        __builtin_amdgcn_sched_barrier(0);
        barrier_c();

        // P2: read B kk1 (4) + stage A(ti+2) into just-freed A slots; MFMA mt0-3 x kk1
#pragma unroll
        for (int nt = 0; nt < 4; nt++) {
            int lr = br0 + nt * 16 + l16;
            b1[nt] = *(const bf16x8*)&Bh[lr * 64 + (((4 + quad) ^ (lr & 7)) * 8)];
        }
        if (ti + 2 < ntt) stageA(ti + 2);
        __builtin_amdgcn_s_setprio(1);
#pragma unroll
        for (int mt = 0; mt < 4; mt++)
#pragma unroll
            for (int nt = 0; nt < 4; nt++)
                acc[mt][nt] = __builtin_amdgcn_mfma_f32_16x16x32_bf16(a1[mt], b1[nt], acc[mt][nt], 0, 0, 0);
        __builtin_amdgcn_s_setprio(0);
        asm volatile("s_waitcnt lgkmcnt(0)" ::: "memory");   // all B-reads landed
        __builtin_amdgcn_sched_barrier(0);
        barrier_c();

        // P3: stage B(ti+2); MFMA mt4-7 x kk1
        if (ti + 2 < ntt) stageB(ti + 2);
        __builtin_amdgcn_s_setprio(1);
#pragma unroll
        for (int mt = 4; mt < 8; mt++)
#pragma unroll
            for (int nt = 0; nt < 4; nt++)
                acc[mt][nt] = __builtin_amdgcn_mfma_f32_16x16x32_bf16(a1[mt], b1[nt], acc[mt][nt], 0, 0, 0);
        __builtin_amdgcn_s_setprio(0);
        // next iteration's vmcnt + barrier closes the tile
    }

    // ---- epilogue: bias+relu -> LDS (swizzled) -> coalesced global stores ----
    barrier_c();                       // all LDS reads done; repurpose smem
    u16* ot = smem;                    // logical [256][256] u16, col ^ (quad<<4)
#pragma unroll
    for (int nt = 0; nt < 4; nt++) {
        float bc = bias[n0 + wc * 64 + nt * 16 + l16];
        int csw = wc * 64 + ((nt ^ quad) * 16) + l16;   // swizzled slot
#pragma unroll
        for (int mt = 0; mt < 8; mt++) {
#pragma unroll
            for (int r = 0; r < 4; r++) {
                int row = wr * 128 + mt * 16 + quad * 4 + r;
                ot[row * 256 + csw] = f2bf(fmaxf(acc[mt][nt][r] + bc, 0.f));
            }
        }
    }
    barrier_c();                       // all writes visible
    int tr = t >> 5, tc = t & 31;
#pragma unroll
    for (int ps = 0; ps < 16; ps++) {
        int row = ps * 16 + tr;
        int qd = (row >> 2) & 3;
        int csw = (tc * 8) ^ (qd << 4);
        bf16x8 v = *(const bf16x8*)&ot[row * 256 + csw];
        *(bf16x8*)&out[(size_t)(m0 + row) * N + n0 + tc * 8] = v;
    }
}

// ---------------- Flash attention ----------------
// XCD-GROUPED dispatch (T1): physical linear block id p (round-robin over 8
// XCDs as p%8) is remapped so all 16 q-tiles of one (b,h) group land on ONE
// XCD: g=p&7, j=p>>3, G=g+8*(j&7), qt0=j>>3 -> (hh,b)=G, qt=(qt0+G)&15.
// Bijective: fixes the measured ~3x K/V over-fetch (each (b,h)'s 512 KB K/V
// panel was replicated into all 8 private L2s -> 128 MB thrash). Per-XCD
// working set now 8 groups x 512 KB = 4 MB = one L2 -> the per-chunk
// __syncthreads DMA-drain waits on L2 (~200cy) instead of HBM (~900cy).
// qt stagger within group keeps causal load balance.
// One q-tile per block; 32 KB LDS -> 4 resident/CU. Per-64-key dbuf staging.
// S^T = K.Q^T via MFMA (operand swap); V^T sigma-perm keys -> PV B-fragment
// is ONE conflict-free XOR-8 ds_read_b128. Row-sum via MFMA with ones.
// No running max (scores bounded; clamp 20); __expf (libm exp2f regressed r7).
__global__ __launch_bounds__(256) void attn_kernel(const u16* __restrict__ Q, int ldq,
                                                   const u16* __restrict__ Kb, int ldk,
                                                   const u16* __restrict__ Vt,
                                                   const int* __restrict__ mask,
                                                   const unsigned char* __restrict__ bmask,
                                                   u16* __restrict__ ctx) {
    __shared__ u16 Ks[2][64 * 64];   // [buf][key][dh], XOR-8 swizzled
    __shared__ u16 Vs[2][64 * 64];   // [buf][dh][perm-key], XOR-8 swizzled
    int t = threadIdx.x;
    int p = (int)(blockIdx.x + 16 * (blockIdx.y + 16 * blockIdx.z));
    int g = p & 7, j = p >> 3;
    int G = g + 8 * (j & 7);          // (b,h) group, all 16 q-tiles same XCD
    int hh = G & 15, b = G >> 4;
    int qt = ((j >> 3) + G) & 15;     // causal stagger within group
    int w = t >> 6, lane = t & 63, quad = lane >> 4, l16 = lane & 15;
    int hoff = hh * DH_;

    bf16x8 ones8;
#pragma unroll
    for (int j2 = 0; j2 < 8; j2++) ones8[j2] = (short)0x3F80;  // bf16 1.0

    // Q fragments (B-operand for S^T), scaled 1/8
    bf16x8 qf[2];
    int qrow = qt * 64 + w * 16 + l16;
#pragma unroll
    for (int kk = 0; kk < 2; kk++) {
        bf16x8 v = *(const bf16x8*)(Q + (size_t)(b * S_ + qrow) * ldq + hoff + kk * 32 + quad * 8);
#pragma unroll
        for (int j2 = 0; j2 < 8; j2++)
            v[j2] = (short)f2bf(bf2f((u16)v[j2]) * 0.125f);
        qf[kk] = v;
    }

    f32x4 oacc[4] = {};
    f32x4 lacc = {};

    // block-mask bitfields over 16 64-key chunks (wave-uniform)
    unsigned nz = 0, mx = 0;
    for (int c = 0; c < 16; c++) {
        int v = bmask ? (int)bmask[(b * 16 + qt) * 16 + c] : 1;
        if (v)      nz |= 1u << c;
        if (v == 1) mx |= 1u << c;
    }

    int sr = lane >> 3;                  // staging row within 8-row group
    int gc = ((lane & 7) ^ sr) * 8;      // swizzled source chunk (u16)

    auto stage64 = [&](int c, int buf) {
        int k0 = c * 64;
        for (int jj = w; jj < 8; jj += 4) {
            gl_lds16(Kb + (size_t)(b * S_ + k0 + jj * 8 + sr) * ldk + hoff + gc, &Ks[buf][jj * 512]);
            gl_lds16(Vt + (size_t)(hoff + jj * 8 + sr) * (B_ * S_) + b * S_ + k0 + gc, &Vs[buf][jj * 512]);
        }
    };

    unsigned rem = nz;
    int c = rem ? __builtin_ctz(rem) : -1;
    if (c >= 0) stage64(c, 0);
    int cur = 0;

    while (c >= 0) {
        rem &= rem - 1;
        int nc = rem ? __builtin_ctz(rem) : -1;
        __syncthreads();                     // drain staging of cur; readers of cur^1 done
        if (nc >= 0) stage64(nc, cur ^ 1);   // DMA overlaps compute below

        int k0c = c * 64;
        bool mixed = (mx >> c) & 1u;
        const u16* KsT = Ks[cur];
        const u16* VsT = Vs[cur];

        // S^T tile: lane holds S[q = qrow][key = k0c+nt*16+quad*4+r]
        float pp[4][4];
#pragma unroll
        for (int nt = 0; nt < 4; nt++) {
            f32x4 sacc = {};
            int krow = nt * 16 + l16;
            __builtin_amdgcn_s_setprio(1);
#pragma unroll
            for (int kk = 0; kk < 2; kk++) {
                int cp = ((kk * 4 + quad) ^ (krow & 7)) * 8;
                bf16x8 kf = *(const bf16x8*)&KsT[krow * 64 + cp];
                sacc = __builtin_amdgcn_mfma_f32_16x16x32_bf16(kf, qf[kk], sacc, 0, 0, 0);
            }
            __builtin_amdgcn_s_setprio(0);
#pragma unroll
            for (int r = 0; r < 4; r++) {
                float sv = sacc[r];
                if (mixed) {
                    int kc = k0c + nt * 16 + quad * 4 + r;
                    if (mask[(size_t)(b * S_ + qrow) * S_ + kc] == 0) sv = -1e9f;
                }
                pp[nt][r] = __expf(fminf(sv, 20.f));
            }
        }

        // PV + rowsum directly from registers (k-slot relabeled x32 MFMA).
        // V-fragment: single b128 read thanks to sigma-permuted Vs layout.
#pragma unroll
        for (int mp = 0; mp < 2; mp++) {
            bf16x8 af;
#pragma unroll
            for (int r = 0; r < 4; r++) {
                af[r]     = (short)f2bf(pp[2 * mp][r]);
                af[4 + r] = (short)f2bf(pp[2 * mp + 1][r]);
            }
            __builtin_amdgcn_s_setprio(1);
            lacc = __builtin_amdgcn_mfma_f32_16x16x32_bf16(af, ones8, lacc, 0, 0, 0);
#pragma unroll
            for (int dt = 0; dt < 4; dt++) {
                int vrow = dt * 16 + l16;
                int ch = (mp * 4 + quad) ^ (vrow & 7);
                bf16x8 vf = *(const bf16x8*)&VsT[vrow * 64 + ch * 8];
                oacc[dt] = __builtin_amdgcn_mfma_f32_16x16x32_bf16(af, vf, oacc[dt], 0, 0, 0);
            }
            __builtin_amdgcn_s_setprio(0);
        }
        c = nc;
        cur ^= 1;
    }

#pragma unroll
    for (int dt = 0; dt < 4; dt++)
#pragma unroll
        for (int r = 0; r < 4; r++) {
            int qq = qt * 64 + w * 16 + quad * 4 + r;
            float l = lacc[r];
            float inv = l > 0.f ? 1.f / l : 0.f;
            ctx[(size_t)(b * S_ + qq) * D_ + hoff + dt * 16 + l16] = f2bf(oacc[dt][r] * inv);
        }
}

extern "C" void kernel_launch(void* const* d_in, const int* in_sizes, int n_in,
                              void* d_out, int out_size, void* d_ws, size_t ws_size,
                              hipStream_t stream) {
    const float* x     = (const float*)d_in[0];
    const float* srcx  = (const float*)d_in[1];
    const int*   mask  = (const int*)d_in[2];
    const int*   smask = (const int*)d_in[3];
    const float* ln1g = (const float*)d_in[4],  *ln1b = (const float*)d_in[5];
    const float* ln2g = (const float*)d_in[6],  *ln2b = (const float*)d_in[7];
    const float* ln3g = (const float*)d_in[8],  *ln3b = (const float*)d_in[9];
    const float* sa_wq = (const float*)d_in[10], *sa_bq = (const float*)d_in[11];
    const float* sa_wk = (const float*)d_in[12], *sa_bk = (const float*)d_in[13];
    const float* sa_wv = (const float*)d_in[14], *sa_bv = (const float*)d_in[15];
    const float* sa_wo = (const float*)d_in[16], *sa_bo = (const float*)d_in[17];
    const float* ca_wq = (const float*)d_in[18], *ca_bq = (const float*)d_in[19];
    const float* ca_wk = (const float*)d_in[20], *ca_bk = (const float*)d_in[21];
    const float* ca_wv = (const float*)d_in[22], *ca_bv = (const float*)d_in[23];
    const float* ca_wo = (const float*)d_in[24], *ca_bo = (const float*)d_in[25];
    const float* ff_w1 = (const float*)d_in[26], *ff_b1 = (const float*)d_in[27];
    const float* ff_w2 = (const float*)d_in[28], *ff_b2 = (const float*)d_in[29];

    char* ws = (char*)d_ws;
    const size_t MB = 1ull << 20;
    const size_t DD = (size_t)D_ * D_;
    float* xcur = (float*)ws;                  // 16 MB fp32 residual
    u16* h     = (u16*)(ws + 16 * MB);         // 8 MB LN output
    u16* qk    = (u16*)(ws + 24 * MB);         // self: [4096][2048] 16 MB
    u16* qb    = (u16*)(ws + 24 * MB);         // cross Q [4096][1024] 8 MB
    u16* kbuf  = (u16*)(ws + 32 * MB);         // cross K 8 MB
    u16* vt    = (u16*)(ws + 40 * MB);         // V^T [1024][4096] 8 MB (perm keys)
    u16* ctx   = (u16*)(ws + 48 * MB);         // 8 MB
    u16* ff    = (u16*)(ws + 24 * MB);         // ffn [4096][4096] 32 MB (reuse)
    u16* sxb   = (u16*)(ws + 56 * MB);         // bf16 src_x 8 MB
    u16* wqk_s = (u16*)(ws + 64 * MB);         // [2048][1024] 4 MB
    u16* wv_s  = (u16*)(ws + 68 * MB);
    u16* wo_s  = (u16*)(ws + 70 * MB);
    u16* wq_c  = (u16*)(ws + 72 * MB);
    u16* wk_c  = (u16*)(ws + 74 * MB);
    u16* wv_c  = (u16*)(ws + 76 * MB);
    u16* wo_c  = (u16*)(ws + 78 * MB);
    u16* wff1  = (u16*)(ws + 80 * MB);         // [4096][1024] 8 MB
    u16* wff2  = (u16*)(ws + 88 * MB);         // [1024][4096] 8 MB
    // FFN2 split-K partials: these regions are dead by FFN time
    // (sxb + staged self/cross weights + wff1 all consumed).
    float* fp0 = (float*)(ws + 56 * MB);       // 16 MB fp32 partial (k 0..2047)
    float* fp1 = (float*)(ws + 72 * MB);       // 16 MB fp32 partial (k 2048..4095)
    unsigned char* bm_self = nullptr, *bm_cross = nullptr;
    if (ws_size >= 96 * MB + 8192) {           // constant across calls -> graph-safe
        bm_self  = (unsigned char*)(ws + ws_size - 8192);
        bm_cross = bm_self + 4096;
    }

    dim3 blk(256);

    // ---- setup: weight transposes, src_x convert, mask classify ----
    TP tp = {{sa_wq, sa_wk, sa_wv, sa_wo, ca_wq, ca_wk, ca_wv, ca_wo},
             {wqk_s, wqk_s + DD, wv_s, wo_s, wq_c, wk_c, wv_c, wo_c}};
    trcvt8_kernel<<<dim3(16, 16, 8), blk, 0, stream>>>(tp);
    trcvt_kernel<<<dim3(F_ / 64, D_ / 64), blk, 0, stream>>>(ff_w1, wff1, D_, F_);
    trcvt_kernel<<<dim3(D_ / 64, F_ / 64), blk, 0, stream>>>(ff_w2, wff2, F_, D_);
    cvt1_kernel<<<B_ * S_ * D_ / 1024, blk, 0, stream>>>(srcx, sxb);
    if (bm_self) {
        mask_reduce_kernel<<<dim3(256, B_), blk, 0, stream>>>(mask, bm_self);
        mask_reduce_kernel<<<dim3(256, B_), blk, 0, stream>>>(smask, bm_cross);
    }

    Bias3 bqk = { sa_bq, sa_bk, sa_bk, 1024, 2048 };
    Bias3 bsv = { sa_bv, sa_bv, sa_bv, 1 << 30, 1 << 30 };
    Bias3 bso = { sa_bo, sa_bo, sa_bo, 1 << 30, 1 << 30 };
    Bias3 bcv = { ca_bv, ca_bv, ca_bv, 1 << 30, 1 << 30 };
    Bias3 bco = { ca_bo, ca_bo, ca_bo, 1 << 30, 1 << 30 };

    // ---- self attention ----
    ln_kernel<true><<<B_ * S_, blk, 0, stream>>>(x, ln1g, ln1b, xcur, h);
    gemm128_kernel<128,128,0,false><<<dim3(16, 32), blk, 0, stream>>>(h, wqk_s, bqk, nullptr, qk, 4096, 2048, 1024);
    gemm128_kernel<64,128,4,true><<<dim3(32, 16), blk, 0, stream>>>(wv_s, h, bsv, nullptr, vt, 1024, 4096, 1024);
    attn_kernel<<<dim3(16, H_, B_), blk, 0, stream>>>(qk, 2048, qk + 1024, 2048, vt, mask, bm_self, ctx);
    gemm128_kernel<128,64,2,false><<<dim3(16, 32), blk, 0, stream>>>(ctx, wo_s, bso, xcur, xcur, 4096, 1024, 1024);

    // ---- cross attention ----
    ln_kernel<false><<<B_ * S_, blk, 0, stream>>>(xcur, ln2g, ln2b, nullptr, h);
    {
        Pair2 pqk = { h, sxb, wq_c, wk_c, ca_bq, ca_bk, qb, kbuf };
        gemm128_pairqk_kernel<<<dim3(8, 32, 2), blk, 0, stream>>>(pqk, 4096, 1024, 1024);
    }
    gemm128_kernel<64,128,4,true><<<dim3(32, 16), blk, 0, stream>>>(wv_c, sxb, bcv, nullptr, vt, 1024, 4096, 1024);
    attn_kernel<<<dim3(16, H_, B_), blk, 0, stream>>>(qb, 1024, kbuf, 1024, vt, smask, bm_cross, ctx);
    gemm128_kernel<128,64,2,false><<<dim3(16, 32), blk, 0, stream>>>(ctx, wo_c, bco, xcur, xcur, 4096, 1024, 1024);

    // ---- FFN ----
    ln_kernel<false><<<B_ * S_, blk, 0, stream>>>(xcur, ln3g, ln3b, nullptr, h);
    gemm8p_kernel<<<dim3(16, 16), dim3(512), 0, stream>>>(h, wff1, ff_b1, ff, 4096, 4096, 1024);
    gemm128_splitk2_kernel<<<dim3(8, 32, 2), blk, 0, stream>>>(ff, wff2, fp0, fp1, 4096, 1024, 2048, 4096);
    ffn2_reduce_kernel<<<dim3(B_ * S_ * D_ / 1024), blk, 0, stream>>>(fp0, fp1, ff_b2, xcur, (float*)d_out);
}